// Round 13
// baseline (211.941 us; speedup 1.0000x reference)
//
#include <hip/hip_runtime.h>
#include <cstdint>

#define EMBED 256
#define HEADS 8
#define LEVELS 4
#define POINTS 4
#define BS 2
#define NQ 16384
#define NV 21760          // 128*128+64*64+32*32+16*16
#define MQ (BS*NQ)        // 32768
#define MV (BS*NV)        // 43520
#define VAL_BLK 340       // MV/128
#define OA_BLK  256       // MQ/128

// prep_k block ranges
#define WT_B  2304        // 6 * 384
#define BKT_B 2368        // +64
#define FB_B  13248       // +MV/4
#define QB_B  21440       // +MQ/4

typedef __attribute__((ext_vector_type(8))) short short8;
typedef __attribute__((ext_vector_type(4))) float f32x4;
typedef __attribute__((ext_vector_type(2))) float f32x2;

__device__ __forceinline__ unsigned short f2bf(float f) {
    unsigned int u = __float_as_uint(f);
    u = (u + 0x7FFFu + ((u >> 16) & 1u)) >> 16;   // RNE
    return (unsigned short)u;
}
__device__ __forceinline__ float bf2f(unsigned short h) {
    return __uint_as_float(((unsigned int)h) << 16);
}
__device__ __forceinline__ void glds16(const unsigned short* g, unsigned short* l) {
    __builtin_amdgcn_global_load_lds((const __attribute__((address_space(1))) void*)g,
                                     (__attribute__((address_space(3))) void*)l, 16, 0, 0);
}

// ---------------------------------------------------------------------------
// prep_k: all elementwise preprocessing in one kernel.
//  [0,2304)      : Wt[n][k] = bf16(W[k][n]) (6 matrices)
//  [2304,2368)   : bkt ids + global hist atomics (hist pre-zeroed by memset)
//  [2368,13248)  : featb[b*NV+n] = bf16(feat[(n*BS+b)])       (4 rows/block)
//  [13248,21440) : qb[b*NQ+n] = bf16(lidar+q_pose), lidarb[(n*BS+b)] = bf16(lidar)
// ---------------------------------------------------------------------------
struct WtArgs {
    const float* src[6];
    unsigned short* dst[6];
    int n[6];
};
__global__ __launch_bounds__(256) void prep_k(
    WtArgs a, const float* __restrict__ ref2d,
    const float* __restrict__ feat, const float* __restrict__ lidar,
    const float* __restrict__ q_pose,
    unsigned short* __restrict__ featb, unsigned short* __restrict__ qb,
    unsigned short* __restrict__ lidarb,
    int* __restrict__ bkt, int* __restrict__ hist)
{
    const int bx = blockIdx.x, t = threadIdx.x;
    if (bx < WT_B) {
        const int g = bx / 384;
        const int e = (bx - g * 384) * 256 + t;
        const int N = a.n[g];
        if (e < 256 * N) {
            const int k = e / N, n = e - k * N;
            a.dst[g][(size_t)n * 256 + k] = f2bf(a.src[g][e]);
        }
    } else if (bx < BKT_B) {
        const int base = (bx - WT_B) * 512;
#pragma unroll
        for (int i = 0; i < 2; ++i) {
            const int rb = base + i * 256 + t;
            const float x = ref2d[(size_t)rb * 8 + 0];
            const float y = ref2d[(size_t)rb * 8 + 1];
            const int qx = min(15, max(0, (int)(x * 16.f)));
            const int qy = min(15, max(0, (int)(y * 16.f)));
            const int bv = (rb >> 14) * 256 + qy * 16 + qx;
            bkt[rb] = bv;
            atomicAdd(&hist[bv], 1);
        }
    } else if (bx < FB_B) {
        const int r = (bx - BKT_B) * 4 + (t >> 6);
        const int c = (t & 63) * 4;
        const int b = r / NV, n = r - b * NV;
        const float4 v4 = *(const float4*)(feat + (size_t)(n * BS + b) * 256 + c);
        ushort4 o; o.x = f2bf(v4.x); o.y = f2bf(v4.y); o.z = f2bf(v4.z); o.w = f2bf(v4.w);
        *(ushort4*)(featb + (size_t)r * 256 + c) = o;
    } else {
        const int r = (bx - FB_B) * 4 + (t >> 6);
        const int c = (t & 63) * 4;
        const int b = r >> 14, n = r & (NQ - 1);
        const size_t src = (size_t)(n * BS + b) * 256 + c;
        const float4 lv = *(const float4*)(lidar + src);
        const float4 qv = *(const float4*)(q_pose + src);
        ushort4 lo; lo.x = f2bf(lv.x); lo.y = f2bf(lv.y); lo.z = f2bf(lv.z); lo.w = f2bf(lv.w);
        *(ushort4*)(lidarb + src) = lo;
        ushort4 qo;
        qo.x = f2bf(lv.x + qv.x); qo.y = f2bf(lv.y + qv.y);
        qo.z = f2bf(lv.z + qv.z); qo.w = f2bf(lv.w + qv.w);
        *(ushort4*)(qb + (size_t)r * 256 + c) = qo;
    }
}

// ---------------------------------------------------------------------------
// gemm_bf: bf16 GEMM tile (128 x NCOLS), glds16 staging both operands
// (same proven structure as outproj_k). out bf16 with bias.
// ---------------------------------------------------------------------------
template<int NCOLS>
__device__ __forceinline__ void gemm_bf(
    unsigned short* As, unsigned short* Bs, int bx,
    const unsigned short* __restrict__ A, const unsigned short* __restrict__ Bt,
    const float* __restrict__ bias0, const float* __restrict__ bias1,
    unsigned short* __restrict__ outh)
{
    constexpr int FN = NCOLS / 64;
    const int t = threadIdx.x, l = t & 63, w = t >> 6;
    const int wm = w >> 2, wn = w & 3;
    const int frow = l & 15, fgrp = l >> 4;
    const size_t brow = (size_t)bx * 128;

    const int fslot = fgrp ^ ((frow & 3) ^ ((frow >> 2) & 3));
    const int srow = l >> 2;
    const int sswz = (l & 3) ^ ((srow & 3) ^ ((srow >> 2) & 3));

    const unsigned short* gA = A + (brow + (size_t)(w * 16 + srow)) * 256 + sswz * 8;
    const unsigned short* gB = Bt + ((size_t)(w * 16 + srow)) * 256 + sswz * 8;

    f32x4 acc[4][FN];
#pragma unroll
    for (int i = 0; i < 4; ++i)
#pragma unroll
        for (int j = 0; j < FN; ++j) acc[i][j] = f32x4{0.f, 0.f, 0.f, 0.f};

    for (int k0 = 0; k0 < 256; k0 += 32) {
        glds16(gB + k0,         &Bs[w * 512]);
        glds16(gB + 32768 + k0, &Bs[(w + 8) * 512]);
        if constexpr (NCOLS == 384)
            glds16(gB + 65536 + k0, &Bs[(w + 16) * 512]);
        glds16(gA + k0, &As[w * 512]);
        __syncthreads();

        short8 af[4]; short8 bq[FN];
#pragma unroll
        for (int fm = 0; fm < 4; ++fm)
            af[fm] = *reinterpret_cast<const short8*>(&As[(wm * 64 + fm * 16 + frow) * 32 + fslot * 8]);
#pragma unroll
        for (int fn = 0; fn < FN; ++fn)
            bq[fn] = *reinterpret_cast<const short8*>(&Bs[(wn * (NCOLS / 4) + fn * 16 + frow) * 32 + fslot * 8]);
#pragma unroll
        for (int fm = 0; fm < 4; ++fm)
#pragma unroll
            for (int fn = 0; fn < FN; ++fn)
                acc[fm][fn] = __builtin_amdgcn_mfma_f32_16x16x32_bf16(af[fm], bq[fn], acc[fm][fn], 0, 0, 0);
        __syncthreads();
    }

#pragma unroll
    for (int fn = 0; fn < FN; ++fn) {
        const int col = wn * (NCOLS / 4) + fn * 16 + frow;
        float b;
        if (NCOLS == 384) b = (col < 256) ? bias0[col] : bias1[col - 256];
        else              b = bias0[col];
#pragma unroll
        for (int fm = 0; fm < 4; ++fm)
#pragma unroll
            for (int j = 0; j < 4; ++j) {
                const size_t row = brow + wm * 64 + fm * 16 + fgrp * 4 + j;
                outh[row * NCOLS + col] = f2bf(acc[fm][fn][j] + b);
            }
    }
}

// ---------------------------------------------------------------------------
// valoa_k: [0,340) value-proj (featb @ Wv); [340,596) off+attn (qb @ Woa);
// block 596: scan hist + scatter perm (R11-proven).
// ---------------------------------------------------------------------------
__global__ __launch_bounds__(512) void valoa_k(
    const unsigned short* __restrict__ featb, const unsigned short* __restrict__ qb,
    const unsigned short* __restrict__ wt_val, const unsigned short* __restrict__ wt_oa,
    const float* __restrict__ b_val, const float* __restrict__ b_off,
    const float* __restrict__ b_attn,
    unsigned short* __restrict__ vb, unsigned short* __restrict__ oa,
    const int* __restrict__ hist, const int* __restrict__ bkt,
    int* __restrict__ perm)
{
    __shared__ unsigned short As[128 * 32];
    __shared__ unsigned short Bs[384 * 32];
    const int bx = blockIdx.x;
    if (bx < VAL_BLK) {
        gemm_bf<256>(As, Bs, bx, featb, wt_val, b_val, nullptr, vb);
    } else if (bx < VAL_BLK + OA_BLK) {
        gemm_bf<384>(As, Bs, bx - VAL_BLK, qb, wt_oa, b_off, b_attn, oa);
    } else {
        int* s   = (int*)As;
        int* cur = ((int*)As) + 512;
        const int t = threadIdx.x;
        const int v = hist[t];
        s[t] = v;
        __syncthreads();
        int acc = v;
#pragma unroll
        for (int o = 1; o < 512; o <<= 1) {
            const int add = (t >= o) ? s[t - o] : 0;
            __syncthreads();
            acc += add;
            s[t] = acc;
            __syncthreads();
        }
        cur[t] = acc - v;
        __syncthreads();
#pragma unroll 4
        for (int i = 0; i < 64; ++i) {
            const int rb = i * 512 + t;
            const int pos = atomicAdd(&cur[bkt[rb]], 1);
            perm[pos] = rb;
        }
    }
}

// ---------------------------------------------------------------------------
// sampler (R12 verbatim): R6 structure + paired ds_read_b128 descriptors +
// f32x2 pk-fma accumulation. 4 q/block, 256 thr, LDS 18.5KB.
// ---------------------------------------------------------------------------
__global__ __launch_bounds__(256) void sampler_k(
    const unsigned short* __restrict__ oa,    // [MQ][384]: off(256) | aw(128)
    const float* __restrict__ ref2d,          // [MQ][8]
    const unsigned short* __restrict__ v,     // [MV][256]
    const int* __restrict__ perm,             // [MQ] bucket-sorted query ids
    unsigned short* __restrict__ outh)        // [MQ][256] nq-major
{
    const int bid = blockIdx.x;
    const int sbid = (bid & 7) * (MQ / 4 / 8) + (bid >> 3);   // XCD swizzle
    const int q0 = sbid * 4;
    const int t = threadIdx.x;

    __shared__ __align__(16) uint2 s_d[4][8][74];  // [tq][h][c*18+lp], padded

#pragma unroll
    for (int it = 0; it < 2; ++it) {     // 512 descriptors, 2 per thread
        const int item = t + it * 256;
        const int tq = item >> 7, hlp = item & 127;
        const int h = hlp >> 4, lp = hlp & 15, li = lp >> 2;
        const int rb = perm[q0 + tq];
        const int b = rb >> 14;

        const float2 refv = *(const float2*)(ref2d + (size_t)rb * 8 + li * 2);
        const ushort2 offu = *(const ushort2*)(oa + (size_t)rb * 384 + hlp * 2);
        const float ax = bf2f(oa[(size_t)rb * 384 + 256 + hlp]);

        // softmax over the 16-lane (q,h) group
        float m = ax;
#pragma unroll
        for (int o = 1; o < 16; o <<= 1) m = fmaxf(m, __shfl_xor(m, o));
        const float e = __expf(ax - m);
        float sden = e;
#pragma unroll
        for (int o = 1; o < 16; o <<= 1) sden += __shfl_xor(sden, o);
        const float a = e / sden;

        const int Wl[4]  = {128, 64, 32, 16};
        const int S0l[4] = {0, 16384, 20480, 21504};
        const int Wi = Wl[li]; const float Wf = (float)Wi;
        const float x = (refv.x + bf2f(offu.x) / Wf) * Wf - 0.5f;
        const float y = (refv.y + bf2f(offu.y) / Wf) * Wf - 0.5f;
        const float x0f = floorf(x), y0f = floorf(y);
        const float lx = x - x0f, ly = y - y0f;
        const int x0 = (int)x0f, y0 = (int)y0f;
        const float cw[4] = {(1.f - lx) * (1.f - ly) * a, lx * (1.f - ly) * a,
                             (1.f - lx) * ly * a,          lx * ly * a};
        const int base = b * NV + S0l[li];
#pragma unroll
        for (int c = 0; c < 4; ++c) {
            const int xi = x0 + (c & 1), yi = y0 + (c >> 1);
            const bool val = (xi >= 0) & (xi < Wi) & (yi >= 0) & (yi < Wi);
            const int xc = min(max(xi, 0), Wi - 1), yc = min(max(yi, 0), Wi - 1);
            const unsigned int ofs = (unsigned int)(base + yc * Wi + xc) * 256u + h * 32;
            s_d[tq][h][c * 18 + lp] = make_uint2(__float_as_uint(val ? cw[c] : 0.f), ofs);
        }
    }
    __syncthreads();

    const int tq = t >> 6, l = t & 63, h = l >> 3, dq = l & 7;
    const int rb = perm[q0 + tq], b = rb >> 14, qi = rb & (NQ - 1);
    const unsigned short* vd = v + dq * 4;
    const uint2* dp = &s_d[tq][h][0];
    f32x2 acc01 = {0.f, 0.f}, acc23 = {0.f, 0.f};
#pragma unroll
    for (int c = 0; c < 4; ++c) {
#pragma unroll
        for (int i = 0; i < 8; ++i) {
            const uint4 dd = *(const uint4*)(dp + c * 18 + i * 2);  // 2 descriptors
            {
                const uint2 raw = *(const uint2*)(vd + dd.y);
                const float w0 = __uint_as_float(dd.x);
                f32x2 v01; v01.x = __uint_as_float(raw.x << 16);
                           v01.y = __uint_as_float(raw.x & 0xFFFF0000u);
                f32x2 v23; v23.x = __uint_as_float(raw.y << 16);
                           v23.y = __uint_as_float(raw.y & 0xFFFF0000u);
                acc01 += w0 * v01;
                acc23 += w0 * v23;
            }
            {
                const uint2 raw = *(const uint2*)(vd + dd.w);
                const float w1 = __uint_as_float(dd.z);
                f32x2 v01; v01.x = __uint_as_float(raw.x << 16);
                           v01.y = __uint_as_float(raw.x & 0xFFFF0000u);
                f32x2 v23; v23.x = __uint_as_float(raw.y << 16);
                           v23.y = __uint_as_float(raw.y & 0xFFFF0000u);
                acc01 += w1 * v01;
                acc23 += w1 * v23;
            }
        }
    }
    ushort4 o;
    o.x = f2bf(acc01.x); o.y = f2bf(acc01.y);
    o.z = f2bf(acc23.x); o.w = f2bf(acc23.y);
    *(ushort4*)(outh + (size_t)(qi * BS + b) * 256 + h * 32 + dq * 4) = o;
}

// ---------------------------------------------------------------------------
// outproj_k: 128-row tile; x = LN1(smp@Wo + b_out + lidarb) -> xln bf16.
// ---------------------------------------------------------------------------
__global__ __launch_bounds__(512) void outproj_k(
    const unsigned short* __restrict__ smp, const unsigned short* __restrict__ lidarb,
    const unsigned short* __restrict__ Wo, const float* __restrict__ b_out,
    const float* __restrict__ ln1g, const float* __restrict__ ln1b,
    unsigned short* __restrict__ xln)
{
    __shared__ unsigned short As[128 * 32];
    __shared__ unsigned short Bs[256 * 32];
    __shared__ float2 sdLN[128][4];

    const int t = threadIdx.x, l = t & 63, w = t >> 6;
    const int wm = w >> 2, wn = w & 3;
    const int frow = l & 15, fgrp = l >> 4;
    const size_t brow = (size_t)blockIdx.x * 128;

    const int fslot = fgrp ^ ((frow & 3) ^ ((frow >> 2) & 3));
    const int srow = l >> 2;
    const int sswz = (l & 3) ^ ((srow & 3) ^ ((srow >> 2) & 3));

    const unsigned short* gA = smp + (brow + (size_t)(w * 16 + srow)) * 256 + sswz * 8;
    const unsigned short* gB = Wo + ((size_t)(w * 16 + srow)) * 256 + sswz * 8;

    f32x4 acc[4][4];
#pragma unroll
    for (int i = 0; i < 4; ++i)
#pragma unroll
        for (int j = 0; j < 4; ++j) acc[i][j] = f32x4{0.f, 0.f, 0.f, 0.f};

    for (int k0 = 0; k0 < 256; k0 += 32) {
        glds16(gB + k0,         &Bs[w * 512]);
        glds16(gB + 32768 + k0, &Bs[(w + 8) * 512]);
        glds16(gA + k0, &As[w * 512]);
        __syncthreads();

        short8 af[4], bq[4];
#pragma unroll
        for (int fm = 0; fm < 4; ++fm)
            af[fm] = *reinterpret_cast<const short8*>(&As[(wm * 64 + fm * 16 + frow) * 32 + fslot * 8]);
#pragma unroll
        for (int fn = 0; fn < 4; ++fn)
            bq[fn] = *reinterpret_cast<const short8*>(&Bs[(wn * 64 + fn * 16 + frow) * 32 + fslot * 8]);
#pragma unroll
        for (int fm = 0; fm < 4; ++fm)
#pragma unroll
            for (int fn = 0; fn < 4; ++fn)
                acc[fm][fn] = __builtin_amdgcn_mfma_f32_16x16x32_bf16(af[fm], bq[fn], acc[fm][fn], 0, 0, 0);
        __syncthreads();
    }

    int cols[4];
#pragma unroll
    for (int fn = 0; fn < 4; ++fn) cols[fn] = wn * 64 + fn * 16 + frow;

#pragma unroll
    for (int fm = 0; fm < 4; ++fm)
#pragma unroll
        for (int j = 0; j < 4; ++j) {
            const size_t row = brow + wm * 64 + fm * 16 + fgrp * 4 + j;
#pragma unroll
            for (int fn = 0; fn < 4; ++fn)
                acc[fm][fn][j] += b_out[cols[fn]] + bf2f(lidarb[row * 256 + cols[fn]]);
        }

#pragma unroll
    for (int fm = 0; fm < 4; ++fm)
#pragma unroll
        for (int j = 0; j < 4; ++j) {
            float s1 = 0.f, s2 = 0.f;
#pragma unroll
            for (int fn = 0; fn < 4; ++fn) { const float x = acc[fm][fn][j]; s1 += x; s2 += x * x; }
#pragma unroll
            for (int o = 1; o < 16; o <<= 1) { s1 += __shfl_xor(s1, o); s2 += __shfl_xor(s2, o); }
            if (frow == 0)
                sdLN[wm * 64 + fm * 16 + fgrp * 4 + j][wn] = make_float2(s1, s2);
        }
    __syncthreads();
    float gv[4], bv[4];
#pragma unroll
    for (int fn = 0; fn < 4; ++fn) { gv[fn] = ln1g[cols[fn]]; bv[fn] = ln1b[cols[fn]]; }
#pragma unroll
    for (int fm = 0; fm < 4; ++fm)
#pragma unroll
        for (int j = 0; j < 4; ++j) {
            const int rl = wm * 64 + fm * 16 + fgrp * 4 + j;
            const float2 p0 = sdLN[rl][0], p1 = sdLN[rl][1], p2 = sdLN[rl][2], p3 = sdLN[rl][3];
            const float s1 = p0.x + p1.x + p2.x + p3.x;
            const float s2 = p0.y + p1.y + p2.y + p3.y;
            const float mu = s1 * (1.f / 256.f);
            const float var = s2 * (1.f / 256.f) - mu * mu;
            const float rstd = rsqrtf(var + 1e-5f);
            const size_t row = brow + rl;
#pragma unroll
            for (int fn = 0; fn < 4; ++fn)
                xln[row * 256 + cols[fn]] = f2bf((acc[fm][fn][j] - mu) * rstd * gv[fn] + bv[fn]);
        }
}

// ---------------------------------------------------------------------------
// ffn_fused: per 64-row block — h = relu(X@W1); out = LN2(h@W2 + X), f32 out.
// ---------------------------------------------------------------------------
__global__ __launch_bounds__(512) void ffn_fused(
    const unsigned short* __restrict__ X,
    const unsigned short* __restrict__ W1t, const unsigned short* __restrict__ W2t,
    const float* __restrict__ lng, const float* __restrict__ lnb,
    float* __restrict__ outf)
{
    __shared__ unsigned short As[64 * 32];
    __shared__ unsigned short Bs[256 * 32];
    __shared__ unsigned short Hs[64 * 256];
    __shared__ float2 sdLN[64][4];

    const int t = threadIdx.x, l = t & 63, w = t >> 6;
    const int wm = w >> 2, wn = w & 3;
    const int frow = l & 15, fgrp = l >> 4;
    const size_t brow = (size_t)blockIdx.x * 64;

    const int fslot = fgrp ^ ((frow & 3) ^ ((frow >> 2) & 3));
    const int srow = l >> 2;
    const int sswz = (l & 3) ^ ((srow & 3) ^ ((srow >> 2) & 3));

    const unsigned short* gX  = X + (brow + (size_t)((w & 3) * 16 + srow)) * 256 + sswz * 8;
    const unsigned short* gW1 = W1t + ((size_t)(w * 16 + srow)) * 256 + sswz * 8;
    const unsigned short* gW2 = W2t + ((size_t)(w * 16 + srow)) * 256 + sswz * 8;

    f32x4 acc[2][4];

#pragma unroll
    for (int i = 0; i < 2; ++i)
#pragma unroll
        for (int j = 0; j < 4; ++j) acc[i][j] = f32x4{0.f, 0.f, 0.f, 0.f};

    for (int k0 = 0; k0 < 256; k0 += 32) {
        glds16(gW1 + k0,         &Bs[w * 512]);
        glds16(gW1 + 32768 + k0, &Bs[(w + 8) * 512]);
        if (w < 4) glds16(gX + k0, &As[w * 512]);
        __syncthreads();

        short8 af[2], bq[4];
#pragma unroll
        for (int fm = 0; fm < 2; ++fm)
            af[fm] = *reinterpret_cast<const short8*>(&As[(wm * 32 + fm * 16 + frow) * 32 + fslot * 8]);
#pragma unroll
        for (int fn = 0; fn < 4; ++fn)
            bq[fn] = *reinterpret_cast<const short8*>(&Bs[(wn * 64 + fn * 16 + frow) * 32 + fslot * 8]);
#pragma unroll
        for (int fm = 0; fm < 2; ++fm)
#pragma unroll
            for (int fn = 0; fn < 4; ++fn)
                acc[fm][fn] = __builtin_amdgcn_mfma_f32_16x16x32_bf16(af[fm], bq[fn], acc[fm][fn], 0, 0, 0);
        __syncthreads();
    }

#pragma unroll
    for (int fm = 0; fm < 2; ++fm)
#pragma unroll
        for (int fn = 0; fn < 4; ++fn) {
            const int col = wn * 64 + fn * 16 + frow;
#pragma unroll
            for (int j = 0; j < 4; ++j) {
                const int row = wm * 32 + fm * 16 + fgrp * 4 + j;
                const int ss = (col >> 3) ^ (row & 7);
                Hs[row * 256 + ss * 8 + (col & 7)] = f2bf(fmaxf(acc[fm][fn][j], 0.f));
            }
        }
    __syncthreads();

#pragma unroll
    for (int i = 0; i < 2; ++i)
#pragma unroll
        for (int j = 0; j < 4; ++j) acc[i][j] = f32x4{0.f, 0.f, 0.f, 0.f};

    for (int k0 = 0; k0 < 256; k0 += 32) {
        glds16(gW2 + k0,         &Bs[w * 512]);
        glds16(gW2 + 32768 + k0, &Bs[(w + 8) * 512]);
        __syncthreads();

        short8 af[2], bq[4];
#pragma unroll
        for (int fm = 0; fm < 2; ++fm) {
            const int row = wm * 32 + fm * 16 + frow;
            const int ksg = (k0 >> 3) + fgrp;
            const int ss = ksg ^ (row & 7);
            af[fm] = *reinterpret_cast<const short8*>(&Hs[row * 256 + ss * 8]);
        }
#pragma unroll
        for (int fn = 0; fn < 4; ++fn)
            bq[fn] = *reinterpret_cast<const short8*>(&Bs[(wn * 64 + fn * 16 + frow) * 32 + fslot * 8]);
#pragma unroll
        for (int fm = 0; fm < 2; ++fm)
#pragma unroll
            for (int fn = 0; fn < 4; ++fn)
                acc[fm][fn] = __builtin_amdgcn_mfma_f32_16x16x32_bf16(af[fm], bq[fn], acc[fm][fn], 0, 0, 0);
        __syncthreads();
    }

#pragma unroll
    for (int fm = 0; fm < 2; ++fm)
#pragma unroll
        for (int fn = 0; fn < 4; ++fn) {
            const int col = wn * 64 + fn * 16 + frow;
#pragma unroll
            for (int j = 0; j < 4; ++j) {
                const size_t row = brow + wm * 32 + fm * 16 + fgrp * 4 + j;
                acc[fm][fn][j] += bf2f(X[row * 256 + col]);
            }
        }
#pragma unroll
    for (int fm = 0; fm < 2; ++fm)
#pragma unroll
        for (int j = 0; j < 4; ++j) {
            float s1 = 0.f, s2 = 0.f;
#pragma unroll
            for (int fn = 0; fn < 4; ++fn) { const float x = acc[fm][fn][j]; s1 += x; s2 += x * x; }
#pragma unroll
            for (int o = 1; o < 16; o <<= 1) { s1 += __shfl_xor(s1, o); s2 += __shfl_xor(s2, o); }
            if (frow == 0)
                sdLN[wm * 32 + fm * 16 + fgrp * 4 + j][wn] = make_float2(s1, s2);
        }
    __syncthreads();
#pragma unroll
    for (int fm = 0; fm < 2; ++fm)
#pragma unroll
        for (int j = 0; j < 4; ++j) {
            const int rl = wm * 32 + fm * 16 + fgrp * 4 + j;
            const float2 p0 = sdLN[rl][0], p1 = sdLN[rl][1], p2 = sdLN[rl][2], p3 = sdLN[rl][3];
            const float s1 = p0.x + p1.x + p2.x + p3.x;
            const float s2 = p0.y + p1.y + p2.y + p3.y;
            const float mu = s1 * (1.f / 256.f);
            const float var = s2 * (1.f / 256.f) - mu * mu;
            const float rstd = rsqrtf(var + 1e-5f);
            const size_t row = brow + rl;
#pragma unroll
            for (int fn = 0; fn < 4; ++fn) {
                const int col = wn * 64 + fn * 16 + frow;
                outf[row * 256 + col] = (acc[fm][fn][j] - mu) * rstd * lng[col] + lnb[col];
            }
        }
}

// ---------------------------------------------------------------------------
extern "C" void kernel_launch(void* const* d_in, const int* in_sizes, int n_in,
                              void* d_out, int out_size, void* d_ws, size_t ws_size,
                              hipStream_t stream)
{
    const float* lidar  = (const float*)d_in[0];
    const float* feat   = (const float*)d_in[1];
    const float* ref2d  = (const float*)d_in[2];
    const float* q_pose = (const float*)d_in[5];
    const float* W_off  = (const float*)d_in[6];
    const float* b_off  = (const float*)d_in[7];
    const float* W_attn = (const float*)d_in[8];
    const float* b_attn = (const float*)d_in[9];
    const float* W_val  = (const float*)d_in[10];
    const float* b_val  = (const float*)d_in[11];
    const float* W_out  = (const float*)d_in[12];
    const float* b_out  = (const float*)d_in[13];
    const float* ln1_g  = (const float*)d_in[14];
    const float* ln1_b  = (const float*)d_in[15];
    const float* ffn_w1 = (const float*)d_in[16];
    const float* ffn_w2 = (const float*)d_in[17];
    const float* ln2_g  = (const float*)d_in[18];
    const float* ln2_b  = (const float*)d_in[19];

    float* out = (float*)d_out;
    char*  ws  = (char*)d_ws;

    // byte offsets; high-water ~104.3 MB (featb aliases xln, qb aliases smp)
    unsigned short* vb     = (unsigned short*)(ws + 0);          // 22,282,240
    unsigned short* oa     = (unsigned short*)(ws + 22282240);   // 25,165,824
    unsigned short* smp    = (unsigned short*)(ws + 47448064);   // 16,777,216
    unsigned short* qb     = smp;                                // alias (dead before sampler writes smp)
    unsigned short* xln    = (unsigned short*)(ws + 64225280);   // 16,777,216
    unsigned short* featb  = xln;                                // alias (dead before outproj writes xln)
    unsigned short* lidarb = (unsigned short*)(ws + 86507520);   // 16,777,216 (featb spans 22.3MB)
    unsigned short* wt     = (unsigned short*)(ws + 103284736);  //    720,896
    int* perm = (int*)(ws + 104005632);                          //    131,072
    int* bkt  = (int*)(ws + 104136704);                          //    131,072
    int* hist = (int*)(ws + 104267776);                          //      2,048
    unsigned short* wt_val = wt;
    unsigned short* wt_oa  = wt + 65536;          // [384][256]
    unsigned short* wt_out = wt + 163840;
    unsigned short* wt_f1  = wt + 229376;
    unsigned short* wt_f2  = wt + 294912;

    WtArgs wa;
    wa.src[0] = W_val;  wa.dst[0] = wt_val;          wa.n[0] = 256;
    wa.src[1] = W_off;  wa.dst[1] = wt_oa;           wa.n[1] = 256;
    wa.src[2] = W_attn; wa.dst[2] = wt_oa + 65536;   wa.n[2] = 128;
    wa.src[3] = W_out;  wa.dst[3] = wt_out;          wa.n[3] = 256;
    wa.src[4] = ffn_w1; wa.dst[4] = wt_f1;           wa.n[4] = 256;
    wa.src[5] = ffn_w2; wa.dst[5] = wt_f2;           wa.n[5] = 256;

    // 0. zero bucket histogram
    hipMemsetAsync(hist, 0, 2048, stream);

    // 1. all elementwise prep: wt transpose, bkt+hist, featb, qb, lidarb
    prep_k<<<dim3(QB_B), dim3(256), 0, stream>>>(
        wa, ref2d, feat, lidar, q_pose, featb, qb, lidarb, bkt, hist);

    // 2. value-proj + off/attn-proj (bf16 glds16 path) + scan/scatter block
    valoa_k<<<dim3(VAL_BLK + OA_BLK + 1), dim3(512), 0, stream>>>(
        featb, qb, wt_val, wt_oa, b_val, b_off, b_attn,
        vb, oa, hist, bkt, perm);

    // 3. deformable sampling (+softmax), sorted order -> smp bf16 nq-major
    sampler_k<<<dim3(MQ / 4), dim3(256), 0, stream>>>(oa, ref2d, vb, perm, smp);

    // 4. out-proj + LN1 -> xln bf16
    outproj_k<<<dim3(MQ / 128), dim3(512), 0, stream>>>(
        smp, lidarb, wt_out, b_out, ln1_g, ln1_b, xln);

    // 5. FFN1+FFN2+LN2 -> d_out f32
    ffn_fused<<<dim3(MQ / 64), dim3(512), 0, stream>>>(
        xln, wt_f1, wt_f2, ln2_g, ln2_b, out);
}

// Round 14
// 207.830 us; speedup vs baseline: 1.0198x; 1.0198x over previous
//
#include <hip/hip_runtime.h>
#include <cstdint>

#define EMBED 256
#define HEADS 8
#define LEVELS 4
#define POINTS 4
#define BS 2
#define NQ 16384
#define NV 21760          // 128*128+64*64+32*32+16*16
#define MQ (BS*NQ)        // 32768
#define MV (BS*NV)        // 43520
#define VAL32 1360        // MV/32
#define OA32  1024        // MQ/32

typedef __attribute__((ext_vector_type(8))) short short8;
typedef __attribute__((ext_vector_type(4))) float f32x4;
typedef __attribute__((ext_vector_type(2))) float f32x2;

__device__ __forceinline__ unsigned short f2bf(float f) {
    unsigned int u = __float_as_uint(f);
    u = (u + 0x7FFFu + ((u >> 16) & 1u)) >> 16;   // RNE
    return (unsigned short)u;
}
__device__ __forceinline__ float bf2f(unsigned short h) {
    return __uint_as_float(((unsigned int)h) << 16);
}
__device__ __forceinline__ void glds16(const unsigned short* g, unsigned short* l) {
    __builtin_amdgcn_global_load_lds((const __attribute__((address_space(1))) void*)g,
                                     (__attribute__((address_space(3))) void*)l, 16, 0, 0);
}

// ---------------------------------------------------------------------------
// prep_wt: y<6 -> Wt[n][k] = bf16(W[k][n]); y==6 -> bucket ids + hist atomics
// (hist zeroed by hipMemsetAsync).
// ---------------------------------------------------------------------------
struct WtArgs {
    const float* src[6];
    unsigned short* dst[6];
    int n[6];
};
__global__ __launch_bounds__(256) void prep_wt(
    WtArgs a, const float* __restrict__ ref2d,
    int* __restrict__ bkt, int* __restrict__ hist)
{
    const int t = threadIdx.x, g = blockIdx.y, bx = blockIdx.x;
    if (g == 6) {
        if (bx < 64) {
#pragma unroll
            for (int i = 0; i < 2; ++i) {
                const int rb = bx * 512 + i * 256 + t;
                const float x = ref2d[(size_t)rb * 8 + 0];
                const float y = ref2d[(size_t)rb * 8 + 1];
                const int qx = min(15, max(0, (int)(x * 16.f)));
                const int qy = min(15, max(0, (int)(y * 16.f)));
                const int bv = (rb >> 14) * 256 + qy * 16 + qx;
                bkt[rb] = bv;
                atomicAdd(&hist[bv], 1);
            }
        }
        return;
    }
    const int N = a.n[g];
    const int e = bx * 256 + t;
    if (e >= 256 * N) return;
    const int k = e / N, n = e - k * N;
    a.dst[g][(size_t)n * 256 + k] = f2bf(a.src[g][e]);
}

// ---------------------------------------------------------------------------
// gemm32: 32-row x NCOLS tile, 256 thr = 4 waves (all split in N).
// A: f32 (+A2) reg-staged with (seq,bs,C) row-remap + cvt -> LDS (swizzled).
// B: glds16. Low VGPR (acc[2][FN]) -> high occupancy; fine-grain blocks.
// lidarb != null: side-write bf16(A) rows in source order.
// ---------------------------------------------------------------------------
template<int NCOLS>
__device__ __forceinline__ void gemm32(
    unsigned short* As, unsigned short* Bs, int bx,
    const float* __restrict__ Af, const float* __restrict__ A2f, int inner,
    const unsigned short* __restrict__ Bt,
    const float* __restrict__ bias0, const float* __restrict__ bias1,
    unsigned short* __restrict__ lidarb, unsigned short* __restrict__ outh)
{
    constexpr int FN = NCOLS / 64;          // frags per wave: 4 (256) / 6 (384)
    const int t = threadIdx.x, l = t & 63, w = t >> 6;   // 4 waves, wn = w
    const int frow = l & 15, fgrp = l >> 4;
    const size_t brow = (size_t)bx * 32;

    const int fslot = fgrp ^ ((frow & 3) ^ ((frow >> 2) & 3));
    const int srow = l >> 2;
    const int sswz = (l & 3) ^ ((srow & 3) ^ ((srow >> 2) & 3));
    const unsigned short* gB0 = Bt + ((size_t)(w * 16 + srow)) * 256 + sswz * 8;

    // A staging: 32 rows x 32 k / 256 thr = 4 f32 each (8 thr per row)
    const int arow = t >> 3;
    const int acol = (t & 7) * 4;
    const int grow = (int)brow + arow;
    const int bidx = grow / inner, nn = grow - bidx * inner;
    const size_t srcrow = (size_t)(nn * BS + bidx) * 256;
    const float* srcA = Af + srcrow;
    const float* srcA2 = A2f ? A2f + srcrow : nullptr;
    const int aslot = (t & 7) >> 1, ahalf = t & 1;
    const int aswz = aslot ^ ((arow & 3) ^ ((arow >> 2) & 3));
    const int aoff = arow * 32 + aswz * 8 + ahalf * 4;

    f32x4 acc[2][FN];
#pragma unroll
    for (int i = 0; i < 2; ++i)
#pragma unroll
        for (int j = 0; j < FN; ++j) acc[i][j] = f32x4{0.f, 0.f, 0.f, 0.f};

    float4 pA = *(const float4*)(srcA + acol);
    float4 pC;
    if (srcA2) pC = *(const float4*)(srcA2 + acol);

    for (int k0 = 0; k0 < 256; k0 += 32) {
#pragma unroll
        for (int c = 0; c < FN; ++c)
            glds16(gB0 + c * 16384 + k0, &Bs[(c * 4 + w) * 512]);

        if (lidarb) {   // bf16(lidar) side-copy, source order
            ushort4 lk;
            lk.x = f2bf(pA.x); lk.y = f2bf(pA.y); lk.z = f2bf(pA.z); lk.w = f2bf(pA.w);
            *(ushort4*)(lidarb + srcrow + k0 + acol) = lk;
        }
        float c0 = pA.x, c1 = pA.y, c2 = pA.z, c3 = pA.w;
        if (srcA2) { c0 += pC.x; c1 += pC.y; c2 += pC.z; c3 += pC.w; }
        ushort4 pk; pk.x = f2bf(c0); pk.y = f2bf(c1); pk.z = f2bf(c2); pk.w = f2bf(c3);
        *(ushort4*)(&As[aoff]) = pk;

        if (k0 + 32 < 256) {
            pA = *(const float4*)(srcA + k0 + 32 + acol);
            if (srcA2) pC = *(const float4*)(srcA2 + k0 + 32 + acol);
        }
        __syncthreads();

        short8 af[2]; short8 bq[FN];
#pragma unroll
        for (int fm = 0; fm < 2; ++fm)
            af[fm] = *reinterpret_cast<const short8*>(&As[(fm * 16 + frow) * 32 + fslot * 8]);
#pragma unroll
        for (int fn = 0; fn < FN; ++fn)
            bq[fn] = *reinterpret_cast<const short8*>(&Bs[(w * (NCOLS / 4) + fn * 16 + frow) * 32 + fslot * 8]);
#pragma unroll
        for (int fm = 0; fm < 2; ++fm)
#pragma unroll
            for (int fn = 0; fn < FN; ++fn)
                acc[fm][fn] = __builtin_amdgcn_mfma_f32_16x16x32_bf16(af[fm], bq[fn], acc[fm][fn], 0, 0, 0);
        __syncthreads();
    }

#pragma unroll
    for (int fn = 0; fn < FN; ++fn) {
        const int col = w * (NCOLS / 4) + fn * 16 + frow;
        float b;
        if (NCOLS == 384) b = (col < 256) ? bias0[col] : bias1[col - 256];
        else              b = bias0[col];
#pragma unroll
        for (int fm = 0; fm < 2; ++fm)
#pragma unroll
            for (int j = 0; j < 4; ++j) {
                const size_t row = brow + fm * 16 + fgrp * 4 + j;
                outh[row * NCOLS + col] = f2bf(acc[fm][fn][j] + b);
            }
    }
}

// ---------------------------------------------------------------------------
// valoa_k: [0,1360) value-proj 32-row tiles; [1360,2384) off+attn (+lidarb);
// block 2384: pair-scan hist + scatter perm (256 thr).
// ---------------------------------------------------------------------------
__global__ __launch_bounds__(256) void valoa_k(
    const float* __restrict__ feat, const float* __restrict__ lidar,
    const float* __restrict__ q_pose,
    const unsigned short* __restrict__ wt_val, const unsigned short* __restrict__ wt_oa,
    const float* __restrict__ b_val, const float* __restrict__ b_off,
    const float* __restrict__ b_attn,
    unsigned short* __restrict__ vb, unsigned short* __restrict__ oa,
    unsigned short* __restrict__ lidarb,
    const int* __restrict__ hist, const int* __restrict__ bkt,
    int* __restrict__ perm)
{
    __shared__ unsigned short As[32 * 32];     // 2KB
    __shared__ unsigned short Bs[384 * 32];    // 24KB
    const int bx = blockIdx.x;
    if (bx < VAL32) {
        gemm32<256>(As, Bs, bx, feat, nullptr, NV, wt_val, b_val, nullptr, nullptr, vb);
    } else if (bx < VAL32 + OA32) {
        gemm32<384>(As, Bs, bx - VAL32, lidar, q_pose, NQ, wt_oa, b_off, b_attn, lidarb, oa);
    } else {
        int* ps  = (int*)As;            // 256 ints
        int* cur = (int*)Bs;            // 512 ints
        const int t = threadIdx.x;
        const int2 hv = ((const int2*)hist)[t];
        const int pair = hv.x + hv.y;
        ps[t] = pair;
        __syncthreads();
        int acc = pair;
#pragma unroll
        for (int o = 1; o < 256; o <<= 1) {
            const int add = (t >= o) ? ps[t - o] : 0;
            __syncthreads();
            acc += add;
            ps[t] = acc;
            __syncthreads();
        }
        const int excl = acc - pair;    // exclusive prefix of pair t
        cur[2 * t]     = excl;
        cur[2 * t + 1] = excl + hv.x;
        __syncthreads();
#pragma unroll 4
        for (int i = 0; i < 128; ++i) {
            const int rb = i * 256 + t;
            const int pos = atomicAdd(&cur[bkt[rb]], 1);
            perm[pos] = rb;
        }
    }
}

// ---------------------------------------------------------------------------
// sampler (R12 verbatim): R6 structure + paired ds_read_b128 descriptors +
// f32x2 pk-fma accumulation. 4 q/block, 256 thr, LDS 18.5KB.
// ---------------------------------------------------------------------------
__global__ __launch_bounds__(256) void sampler_k(
    const unsigned short* __restrict__ oa,    // [MQ][384]: off(256) | aw(128)
    const float* __restrict__ ref2d,          // [MQ][8]
    const unsigned short* __restrict__ v,     // [MV][256]
    const int* __restrict__ perm,             // [MQ] bucket-sorted query ids
    unsigned short* __restrict__ outh)        // [MQ][256] nq-major
{
    const int bid = blockIdx.x;
    const int sbid = (bid & 7) * (MQ / 4 / 8) + (bid >> 3);   // XCD swizzle
    const int q0 = sbid * 4;
    const int t = threadIdx.x;

    __shared__ __align__(16) uint2 s_d[4][8][74];  // [tq][h][c*18+lp], padded

#pragma unroll
    for (int it = 0; it < 2; ++it) {     // 512 descriptors, 2 per thread
        const int item = t + it * 256;
        const int tq = item >> 7, hlp = item & 127;
        const int h = hlp >> 4, lp = hlp & 15, li = lp >> 2;
        const int rb = perm[q0 + tq];
        const int b = rb >> 14;

        const float2 refv = *(const float2*)(ref2d + (size_t)rb * 8 + li * 2);
        const ushort2 offu = *(const ushort2*)(oa + (size_t)rb * 384 + hlp * 2);
        const float ax = bf2f(oa[(size_t)rb * 384 + 256 + hlp]);

        // softmax over the 16-lane (q,h) group
        float m = ax;
#pragma unroll
        for (int o = 1; o < 16; o <<= 1) m = fmaxf(m, __shfl_xor(m, o));
        const float e = __expf(ax - m);
        float sden = e;
#pragma unroll
        for (int o = 1; o < 16; o <<= 1) sden += __shfl_xor(sden, o);
        const float a = e / sden;

        const int Wl[4]  = {128, 64, 32, 16};
        const int S0l[4] = {0, 16384, 20480, 21504};
        const int Wi = Wl[li]; const float Wf = (float)Wi;
        const float x = (refv.x + bf2f(offu.x) / Wf) * Wf - 0.5f;
        const float y = (refv.y + bf2f(offu.y) / Wf) * Wf - 0.5f;
        const float x0f = floorf(x), y0f = floorf(y);
        const float lx = x - x0f, ly = y - y0f;
        const int x0 = (int)x0f, y0 = (int)y0f;
        const float cw[4] = {(1.f - lx) * (1.f - ly) * a, lx * (1.f - ly) * a,
                             (1.f - lx) * ly * a,          lx * ly * a};
        const int base = b * NV + S0l[li];
#pragma unroll
        for (int c = 0; c < 4; ++c) {
            const int xi = x0 + (c & 1), yi = y0 + (c >> 1);
            const bool val = (xi >= 0) & (xi < Wi) & (yi >= 0) & (yi < Wi);
            const int xc = min(max(xi, 0), Wi - 1), yc = min(max(yi, 0), Wi - 1);
            const unsigned int ofs = (unsigned int)(base + yc * Wi + xc) * 256u + h * 32;
            s_d[tq][h][c * 18 + lp] = make_uint2(__float_as_uint(val ? cw[c] : 0.f), ofs);
        }
    }
    __syncthreads();

    const int tq = t >> 6, l = t & 63, h = l >> 3, dq = l & 7;
    const int rb = perm[q0 + tq], b = rb >> 14, qi = rb & (NQ - 1);
    const unsigned short* vd = v + dq * 4;
    const uint2* dp = &s_d[tq][h][0];
    f32x2 acc01 = {0.f, 0.f}, acc23 = {0.f, 0.f};
#pragma unroll
    for (int c = 0; c < 4; ++c) {
#pragma unroll
        for (int i = 0; i < 8; ++i) {
            const uint4 dd = *(const uint4*)(dp + c * 18 + i * 2);  // 2 descriptors
            {
                const uint2 raw = *(const uint2*)(vd + dd.y);
                const float w0 = __uint_as_float(dd.x);
                f32x2 v01; v01.x = __uint_as_float(raw.x << 16);
                           v01.y = __uint_as_float(raw.x & 0xFFFF0000u);
                f32x2 v23; v23.x = __uint_as_float(raw.y << 16);
                           v23.y = __uint_as_float(raw.y & 0xFFFF0000u);
                acc01 += w0 * v01;
                acc23 += w0 * v23;
            }
            {
                const uint2 raw = *(const uint2*)(vd + dd.w);
                const float w1 = __uint_as_float(dd.z);
                f32x2 v01; v01.x = __uint_as_float(raw.x << 16);
                           v01.y = __uint_as_float(raw.x & 0xFFFF0000u);
                f32x2 v23; v23.x = __uint_as_float(raw.y << 16);
                           v23.y = __uint_as_float(raw.y & 0xFFFF0000u);
                acc01 += w1 * v01;
                acc23 += w1 * v23;
            }
        }
    }
    ushort4 o;
    o.x = f2bf(acc01.x); o.y = f2bf(acc01.y);
    o.z = f2bf(acc23.x); o.w = f2bf(acc23.y);
    *(ushort4*)(outh + (size_t)(qi * BS + b) * 256 + h * 32 + dq * 4) = o;
}

// ---------------------------------------------------------------------------
// outproj_k (R12 verbatim): 128-row tile; x = LN1(smp@Wo + b_out + lidarb).
// ---------------------------------------------------------------------------
__global__ __launch_bounds__(512) void outproj_k(
    const unsigned short* __restrict__ smp, const unsigned short* __restrict__ lidarb,
    const unsigned short* __restrict__ Wo, const float* __restrict__ b_out,
    const float* __restrict__ ln1g, const float* __restrict__ ln1b,
    unsigned short* __restrict__ xln)
{
    __shared__ unsigned short As[128 * 32];
    __shared__ unsigned short Bs[256 * 32];
    __shared__ float2 sdLN[128][4];

    const int t = threadIdx.x, l = t & 63, w = t >> 6;
    const int wm = w >> 2, wn = w & 3;
    const int frow = l & 15, fgrp = l >> 4;
    const size_t brow = (size_t)blockIdx.x * 128;

    const int fslot = fgrp ^ ((frow & 3) ^ ((frow >> 2) & 3));
    const int srow = l >> 2;
    const int sswz = (l & 3) ^ ((srow & 3) ^ ((srow >> 2) & 3));

    const unsigned short* gA = smp + (brow + (size_t)(w * 16 + srow)) * 256 + sswz * 8;
    const unsigned short* gB = Wo + ((size_t)(w * 16 + srow)) * 256 + sswz * 8;

    f32x4 acc[4][4];
#pragma unroll
    for (int i = 0; i < 4; ++i)
#pragma unroll
        for (int j = 0; j < 4; ++j) acc[i][j] = f32x4{0.f, 0.f, 0.f, 0.f};

    for (int k0 = 0; k0 < 256; k0 += 32) {
        glds16(gB + k0,         &Bs[w * 512]);
        glds16(gB + 32768 + k0, &Bs[(w + 8) * 512]);
        glds16(gA + k0, &As[w * 512]);
        __syncthreads();

        short8 af[4], bq[4];
#pragma unroll
        for (int fm = 0; fm < 4; ++fm)
            af[fm] = *reinterpret_cast<const short8*>(&As[(wm * 64 + fm * 16 + frow) * 32 + fslot * 8]);
#pragma unroll
        for (int fn = 0; fn < 4; ++fn)
            bq[fn] = *reinterpret_cast<const short8*>(&Bs[(wn * 64 + fn * 16 + frow) * 32 + fslot * 8]);
#pragma unroll
        for (int fm = 0; fm < 4; ++fm)
#pragma unroll
            for (int fn = 0; fn < 4; ++fn)
                acc[fm][fn] = __builtin_amdgcn_mfma_f32_16x16x32_bf16(af[fm], bq[fn], acc[fm][fn], 0, 0, 0);
        __syncthreads();
    }

    int cols[4];
#pragma unroll
    for (int fn = 0; fn < 4; ++fn) cols[fn] = wn * 64 + fn * 16 + frow;

#pragma unroll
    for (int fm = 0; fm < 4; ++fm)
#pragma unroll
        for (int j = 0; j < 4; ++j) {
            const size_t row = brow + wm * 64 + fm * 16 + fgrp * 4 + j;
#pragma unroll
            for (int fn = 0; fn < 4; ++fn)
                acc[fm][fn][j] += b_out[cols[fn]] + bf2f(lidarb[row * 256 + cols[fn]]);
        }

#pragma unroll
    for (int fm = 0; fm < 4; ++fm)
#pragma unroll
        for (int j = 0; j < 4; ++j) {
            float s1 = 0.f, s2 = 0.f;
#pragma unroll
            for (int fn = 0; fn < 4; ++fn) { const float x = acc[fm][fn][j]; s1 += x; s2 += x * x; }
#pragma unroll
            for (int o = 1; o < 16; o <<= 1) { s1 += __shfl_xor(s1, o); s2 += __shfl_xor(s2, o); }
            if (frow == 0)
                sdLN[wm * 64 + fm * 16 + fgrp * 4 + j][wn] = make_float2(s1, s2);
        }
    __syncthreads();
    float gv[4], bv[4];
#pragma unroll
    for (int fn = 0; fn < 4; ++fn) { gv[fn] = ln1g[cols[fn]]; bv[fn] = ln1b[cols[fn]]; }
#pragma unroll
    for (int fm = 0; fm < 4; ++fm)
#pragma unroll
        for (int j = 0; j < 4; ++j) {
            const int rl = wm * 64 + fm * 16 + fgrp * 4 + j;
            const float2 p0 = sdLN[rl][0], p1 = sdLN[rl][1], p2 = sdLN[rl][2], p3 = sdLN[rl][3];
            const float s1 = p0.x + p1.x + p2.x + p3.x;
            const float s2 = p0.y + p1.y + p2.y + p3.y;
            const float mu = s1 * (1.f / 256.f);
            const float var = s2 * (1.f / 256.f) - mu * mu;
            const float rstd = rsqrtf(var + 1e-5f);
            const size_t row = brow + rl;
#pragma unroll
            for (int fn = 0; fn < 4; ++fn)
                xln[row * 256 + cols[fn]] = f2bf((acc[fm][fn][j] - mu) * rstd * gv[fn] + bv[fn]);
        }
}

// ---------------------------------------------------------------------------
// ffn_fused (R12 verbatim): h = relu(X@W1); out = LN2(h@W2 + X), f32 out.
// ---------------------------------------------------------------------------
__global__ __launch_bounds__(512) void ffn_fused(
    const unsigned short* __restrict__ X,
    const unsigned short* __restrict__ W1t, const unsigned short* __restrict__ W2t,
    const float* __restrict__ lng, const float* __restrict__ lnb,
    float* __restrict__ outf)
{
    __shared__ unsigned short As[64 * 32];
    __shared__ unsigned short Bs[256 * 32];
    __shared__ unsigned short Hs[64 * 256];
    __shared__ float2 sdLN[64][4];

    const int t = threadIdx.x, l = t & 63, w = t >> 6;
    const int wm = w >> 2, wn = w & 3;
    const int frow = l & 15, fgrp = l >> 4;
    const size_t brow = (size_t)blockIdx.x * 64;

    const int fslot = fgrp ^ ((frow & 3) ^ ((frow >> 2) & 3));
    const int srow = l >> 2;
    const int sswz = (l & 3) ^ ((srow & 3) ^ ((srow >> 2) & 3));

    const unsigned short* gX  = X + (brow + (size_t)((w & 3) * 16 + srow)) * 256 + sswz * 8;
    const unsigned short* gW1 = W1t + ((size_t)(w * 16 + srow)) * 256 + sswz * 8;
    const unsigned short* gW2 = W2t + ((size_t)(w * 16 + srow)) * 256 + sswz * 8;

    f32x4 acc[2][4];

#pragma unroll
    for (int i = 0; i < 2; ++i)
#pragma unroll
        for (int j = 0; j < 4; ++j) acc[i][j] = f32x4{0.f, 0.f, 0.f, 0.f};

    for (int k0 = 0; k0 < 256; k0 += 32) {
        glds16(gW1 + k0,         &Bs[w * 512]);
        glds16(gW1 + 32768 + k0, &Bs[(w + 8) * 512]);
        if (w < 4) glds16(gX + k0, &As[w * 512]);
        __syncthreads();

        short8 af[2], bq[4];
#pragma unroll
        for (int fm = 0; fm < 2; ++fm)
            af[fm] = *reinterpret_cast<const short8*>(&As[(wm * 32 + fm * 16 + frow) * 32 + fslot * 8]);
#pragma unroll
        for (int fn = 0; fn < 4; ++fn)
            bq[fn] = *reinterpret_cast<const short8*>(&Bs[(wn * 64 + fn * 16 + frow) * 32 + fslot * 8]);
#pragma unroll
        for (int fm = 0; fm < 2; ++fm)
#pragma unroll
            for (int fn = 0; fn < 4; ++fn)
                acc[fm][fn] = __builtin_amdgcn_mfma_f32_16x16x32_bf16(af[fm], bq[fn], acc[fm][fn], 0, 0, 0);
        __syncthreads();
    }

#pragma unroll
    for (int fm = 0; fm < 2; ++fm)
#pragma unroll
        for (int fn = 0; fn < 4; ++fn) {
            const int col = wn * 64 + fn * 16 + frow;
#pragma unroll
            for (int j = 0; j < 4; ++j) {
                const int row = wm * 32 + fm * 16 + fgrp * 4 + j;
                const int ss = (col >> 3) ^ (row & 7);
                Hs[row * 256 + ss * 8 + (col & 7)] = f2bf(fmaxf(acc[fm][fn][j], 0.f));
            }
        }
    __syncthreads();

#pragma unroll
    for (int i = 0; i < 2; ++i)
#pragma unroll
        for (int j = 0; j < 4; ++j) acc[i][j] = f32x4{0.f, 0.f, 0.f, 0.f};

    for (int k0 = 0; k0 < 256; k0 += 32) {
        glds16(gW2 + k0,         &Bs[w * 512]);
        glds16(gW2 + 32768 + k0, &Bs[(w + 8) * 512]);
        __syncthreads();

        short8 af[2], bq[4];
#pragma unroll
        for (int fm = 0; fm < 2; ++fm) {
            const int row = wm * 32 + fm * 16 + frow;
            const int ksg = (k0 >> 3) + fgrp;
            const int ss = ksg ^ (row & 7);
            af[fm] = *reinterpret_cast<const short8*>(&Hs[row * 256 + ss * 8]);
        }
#pragma unroll
        for (int fn = 0; fn < 4; ++fn)
            bq[fn] = *reinterpret_cast<const short8*>(&Bs[(wn * 64 + fn * 16 + frow) * 32 + fslot * 8]);
#pragma unroll
        for (int fm = 0; fm < 2; ++fm)
#pragma unroll
            for (int fn = 0; fn < 4; ++fn)
                acc[fm][fn] = __builtin_amdgcn_mfma_f32_16x16x32_bf16(af[fm], bq[fn], acc[fm][fn], 0, 0, 0);
        __syncthreads();
    }

#pragma unroll
    for (int fm = 0; fm < 2; ++fm)
#pragma unroll
        for (int fn = 0; fn < 4; ++fn) {
            const int col = wn * 64 + fn * 16 + frow;
#pragma unroll
            for (int j = 0; j < 4; ++j) {
                const size_t row = brow + wm * 32 + fm * 16 + fgrp * 4 + j;
                acc[fm][fn][j] += bf2f(X[row * 256 + col]);
            }
        }
#pragma unroll
    for (int fm = 0; fm < 2; ++fm)
#pragma unroll
        for (int j = 0; j < 4; ++j) {
            float s1 = 0.f, s2 = 0.f;
#pragma unroll
            for (int fn = 0; fn < 4; ++fn) { const float x = acc[fm][fn][j]; s1 += x; s2 += x * x; }
#pragma unroll
            for (int o = 1; o < 16; o <<= 1) { s1 += __shfl_xor(s1, o); s2 += __shfl_xor(s2, o); }
            if (frow == 0)
                sdLN[wm * 32 + fm * 16 + fgrp * 4 + j][wn] = make_float2(s1, s2);
        }
    __syncthreads();
#pragma unroll
    for (int fm = 0; fm < 2; ++fm)
#pragma unroll
        for (int j = 0; j < 4; ++j) {
            const int rl = wm * 32 + fm * 16 + fgrp * 4 + j;
            const float2 p0 = sdLN[rl][0], p1 = sdLN[rl][1], p2 = sdLN[rl][2], p3 = sdLN[rl][3];
            const float s1 = p0.x + p1.x + p2.x + p3.x;
            const float s2 = p0.y + p1.y + p2.y + p3.y;
            const float mu = s1 * (1.f / 256.f);
            const float var = s2 * (1.f / 256.f) - mu * mu;
            const float rstd = rsqrtf(var + 1e-5f);
            const size_t row = brow + rl;
#pragma unroll
            for (int fn = 0; fn < 4; ++fn) {
                const int col = wn * 64 + fn * 16 + frow;
                outf[row * 256 + col] = (acc[fm][fn][j] - mu) * rstd * lng[col] + lnb[col];
            }
        }
}

// ---------------------------------------------------------------------------
extern "C" void kernel_launch(void* const* d_in, const int* in_sizes, int n_in,
                              void* d_out, int out_size, void* d_ws, size_t ws_size,
                              hipStream_t stream)
{
    const float* lidar  = (const float*)d_in[0];
    const float* feat   = (const float*)d_in[1];
    const float* ref2d  = (const float*)d_in[2];
    const float* q_pose = (const float*)d_in[5];
    const float* W_off  = (const float*)d_in[6];
    const float* b_off  = (const float*)d_in[7];
    const float* W_attn = (const float*)d_in[8];
    const float* b_attn = (const float*)d_in[9];
    const float* W_val  = (const float*)d_in[10];
    const float* b_val  = (const float*)d_in[11];
    const float* W_out  = (const float*)d_in[12];
    const float* b_out  = (const float*)d_in[13];
    const float* ln1_g  = (const float*)d_in[14];
    const float* ln1_b  = (const float*)d_in[15];
    const float* ffn_w1 = (const float*)d_in[16];
    const float* ffn_w2 = (const float*)d_in[17];
    const float* ln2_g  = (const float*)d_in[18];
    const float* ln2_b  = (const float*)d_in[19];

    float* out = (float*)d_out;
    char*  ws  = (char*)d_ws;

    // byte offsets; high-water ~98.8 MB
    unsigned short* vb     = (unsigned short*)(ws + 0);          // 22,282,240
    unsigned short* oa     = (unsigned short*)(ws + 22282240);   // 25,165,824
    unsigned short* smp    = (unsigned short*)(ws + 47448064);   // 16,777,216
    unsigned short* xln    = (unsigned short*)(ws + 64225280);   // 16,777,216
    unsigned short* lidarb = (unsigned short*)(ws + 81002496);   // 16,777,216
    unsigned short* wt     = (unsigned short*)(ws + 97779712);   //    720,896
    int* perm = (int*)(ws + 98500608);                           //    131,072
    int* bkt  = (int*)(ws + 98631680);                           //    131,072
    int* hist = (int*)(ws + 98762752);                           //      2,048
    unsigned short* wt_val = wt;
    unsigned short* wt_oa  = wt + 65536;          // [384][256]
    unsigned short* wt_out = wt + 163840;
    unsigned short* wt_f1  = wt + 229376;
    unsigned short* wt_f2  = wt + 294912;

    WtArgs wa;
    wa.src[0] = W_val;  wa.dst[0] = wt_val;          wa.n[0] = 256;
    wa.src[1] = W_off;  wa.dst[1] = wt_oa;           wa.n[1] = 256;
    wa.src[2] = W_attn; wa.dst[2] = wt_oa + 65536;   wa.n[2] = 128;
    wa.src[3] = W_out;  wa.dst[3] = wt_out;          wa.n[3] = 256;
    wa.src[4] = ffn_w1; wa.dst[4] = wt_f1;           wa.n[4] = 256;
    wa.src[5] = ffn_w2; wa.dst[5] = wt_f2;           wa.n[5] = 256;

    // 0. zero bucket histogram
    hipMemsetAsync(hist, 0, 2048, stream);

    // 1. weight transpose + bucket ids + hist
    prep_wt<<<dim3(384, 7), dim3(256), 0, stream>>>(wa, ref2d, bkt, hist);

    // 2. value-proj + off/attn-proj (+lidar bf16 copy) + scan/scatter
    valoa_k<<<dim3(VAL32 + OA32 + 1), dim3(256), 0, stream>>>(
        feat, lidar, q_pose, wt_val, wt_oa, b_val, b_off, b_attn,
        vb, oa, lidarb, hist, bkt, perm);

    // 3. deformable sampling (+softmax), sorted order -> smp bf16 nq-major
    sampler_k<<<dim3(MQ / 4), dim3(256), 0, stream>>>(oa, ref2d, vb, perm, smp);

    // 4. out-proj + LN1 -> xln bf16
    outproj_k<<<dim3(MQ / 128), dim3(512), 0, stream>>>(
        smp, lidarb, wt_out, b_out, ln1_g, ln1_b, xln);

    // 5. FFN1+FFN2+LN2 -> d_out f32
    ffn_fused<<<dim3(MQ / 64), dim3(512), 0, stream>>>(
        xln, wt_f1, wt_f2, ln2_g, ln2_b, out);
}

// Round 15
// 197.561 us; speedup vs baseline: 1.0728x; 1.0520x over previous
//
#include <hip/hip_runtime.h>
#include <cstdint>

#define EMBED 256
#define HEADS 8
#define LEVELS 4
#define POINTS 4
#define BS 2
#define NQ 16384
#define NV 21760          // 128*128+64*64+32*32+16*16
#define MQ (BS*NQ)        // 32768
#define MV (BS*NV)        // 43520
#define VAL_BLK 340       // MV/128
#define OA_BLK  256       // MQ/128

typedef __attribute__((ext_vector_type(8))) short short8;
typedef __attribute__((ext_vector_type(4))) float f32x4;
typedef __attribute__((ext_vector_type(2))) float f32x2;

__device__ __forceinline__ unsigned short f2bf(float f) {
    unsigned int u = __float_as_uint(f);
    u = (u + 0x7FFFu + ((u >> 16) & 1u)) >> 16;   // RNE
    return (unsigned short)u;
}
__device__ __forceinline__ float bf2f(unsigned short h) {
    return __uint_as_float(((unsigned int)h) << 16);
}
__device__ __forceinline__ void glds16(const unsigned short* g, unsigned short* l) {
    __builtin_amdgcn_global_load_lds((const __attribute__((address_space(1))) void*)g,
                                     (__attribute__((address_space(3))) void*)l, 16, 0, 0);
}

// ---------------------------------------------------------------------------
// prep_wt: y<6 -> Wt[n][k] = bf16(W[k][n]); y==6 -> bucket ids only.
// ---------------------------------------------------------------------------
struct WtArgs {
    const float* src[6];
    unsigned short* dst[6];
    int n[6];
};
__global__ __launch_bounds__(256) void prep_wt(
    WtArgs a, const float* __restrict__ ref2d, int* __restrict__ bkt)
{
    const int t = threadIdx.x, g = blockIdx.y, bx = blockIdx.x;
    if (g == 6) {
        if (bx < 64) {
#pragma unroll
            for (int i = 0; i < 2; ++i) {
                const int rb = bx * 512 + i * 256 + t;
                const float x = ref2d[(size_t)rb * 8 + 0];
                const float y = ref2d[(size_t)rb * 8 + 1];
                const int qx = min(15, max(0, (int)(x * 16.f)));
                const int qy = min(15, max(0, (int)(y * 16.f)));
                bkt[rb] = (rb >> 14) * 256 + qy * 16 + qx;
            }
        }
        return;
    }
    const int N = a.n[g];
    const int e = bx * 256 + t;
    if (e >= 256 * N) return;
    const int k = e / N, n = e - k * N;
    a.dst[g][(size_t)n * 256 + k] = f2bf(a.src[g][e]);
}

// ---------------------------------------------------------------------------
// gemm_core: SOURCE-ORDER rows (no remap -> sequential HBM reads).
// outh[native_row] = bf16(A f32 (+A2)) @ Wt^T + bias; optional lidarb copy.
// ---------------------------------------------------------------------------
template<int NCOLS>
__device__ __forceinline__ void gemm_core(
    unsigned short* As, unsigned short* Bs, int bx,
    const float* __restrict__ Af, const float* __restrict__ A2f,
    const unsigned short* __restrict__ Bt,
    const float* __restrict__ bias0, const float* __restrict__ bias1,
    unsigned short* __restrict__ lidarb, unsigned short* __restrict__ outh)
{
    constexpr int FN = NCOLS / 64;
    const int t = threadIdx.x, l = t & 63, w = t >> 6;
    const int wm = w >> 2, wn = w & 3;
    const int frow = l & 15, fgrp = l >> 4;
    const size_t brow = (size_t)bx * 128;

    const int fslot = fgrp ^ ((frow & 3) ^ ((frow >> 2) & 3));
    const int srow = l >> 2;
    const int sswz = (l & 3) ^ ((srow & 3) ^ ((srow >> 2) & 3));
    const unsigned short* gB0 = Bt + ((size_t)(w * 16 + srow)) * 256 + sswz * 8;

    const int arow_s = t >> 2, aslot_s = t & 3;
    const size_t srcrow = (brow + arow_s) * 256;     // NATIVE row -> sequential
    const float* srcA = Af + srcrow;
    const float* srcA2 = A2f ? A2f + srcrow : nullptr;
    const int aswz_s = aslot_s ^ ((arow_s & 3) ^ ((arow_s >> 2) & 3));

    f32x4 acc[4][FN];
#pragma unroll
    for (int i = 0; i < 4; ++i)
#pragma unroll
        for (int j = 0; j < FN; ++j) acc[i][j] = f32x4{0.f, 0.f, 0.f, 0.f};

    float4 pA0 = *(const float4*)(srcA + aslot_s * 8);
    float4 pA1 = *(const float4*)(srcA + aslot_s * 8 + 4);
    float4 pC0, pC1;
    if (srcA2) { pC0 = *(const float4*)(srcA2 + aslot_s * 8);
                 pC1 = *(const float4*)(srcA2 + aslot_s * 8 + 4); }

    for (int k0 = 0; k0 < 256; k0 += 32) {
        glds16(gB0 + k0,         &Bs[w * 512]);
        glds16(gB0 + 32768 + k0, &Bs[(w + 8) * 512]);
        if constexpr (NCOLS == 384)
            glds16(gB0 + 65536 + k0, &Bs[(w + 16) * 512]);

        if (lidarb) {   // bf16(lidar) side-copy, native order
            short8 lk;
            lk[0] = (short)f2bf(pA0.x); lk[1] = (short)f2bf(pA0.y);
            lk[2] = (short)f2bf(pA0.z); lk[3] = (short)f2bf(pA0.w);
            lk[4] = (short)f2bf(pA1.x); lk[5] = (short)f2bf(pA1.y);
            lk[6] = (short)f2bf(pA1.z); lk[7] = (short)f2bf(pA1.w);
            *reinterpret_cast<short8*>(lidarb + srcrow + k0 + aslot_s * 8) = lk;
        }

        float c[8] = {pA0.x, pA0.y, pA0.z, pA0.w, pA1.x, pA1.y, pA1.z, pA1.w};
        if (srcA2) {
            c[0] += pC0.x; c[1] += pC0.y; c[2] += pC0.z; c[3] += pC0.w;
            c[4] += pC1.x; c[5] += pC1.y; c[6] += pC1.z; c[7] += pC1.w;
        }
        short8 pk;
#pragma unroll
        for (int i = 0; i < 8; ++i) pk[i] = (short)f2bf(c[i]);
        *reinterpret_cast<short8*>(&As[arow_s * 32 + aswz_s * 8]) = pk;
        if (k0 + 32 < 256) {
            pA0 = *(const float4*)(srcA + k0 + 32 + aslot_s * 8);
            pA1 = *(const float4*)(srcA + k0 + 32 + aslot_s * 8 + 4);
            if (srcA2) { pC0 = *(const float4*)(srcA2 + k0 + 32 + aslot_s * 8);
                         pC1 = *(const float4*)(srcA2 + k0 + 32 + aslot_s * 8 + 4); }
        }
        __syncthreads();

        short8 af[4]; short8 bq[FN];
#pragma unroll
        for (int fm = 0; fm < 4; ++fm)
            af[fm] = *reinterpret_cast<const short8*>(&As[(wm * 64 + fm * 16 + frow) * 32 + fslot * 8]);
#pragma unroll
        for (int fn = 0; fn < FN; ++fn)
            bq[fn] = *reinterpret_cast<const short8*>(&Bs[(wn * (NCOLS / 4) + fn * 16 + frow) * 32 + fslot * 8]);
#pragma unroll
        for (int fm = 0; fm < 4; ++fm)
#pragma unroll
            for (int fn = 0; fn < FN; ++fn)
                acc[fm][fn] = __builtin_amdgcn_mfma_f32_16x16x32_bf16(af[fm], bq[fn], acc[fm][fn], 0, 0, 0);
        __syncthreads();
    }

#pragma unroll
    for (int fn = 0; fn < FN; ++fn) {
        const int col = wn * (NCOLS / 4) + fn * 16 + frow;
        float b;
        if (NCOLS == 384) b = (col < 256) ? bias0[col] : bias1[col - 256];
        else              b = bias0[col];
#pragma unroll
        for (int fm = 0; fm < 4; ++fm)
#pragma unroll
            for (int j = 0; j < 4; ++j) {
                const size_t row = brow + wm * 64 + fm * 16 + fgrp * 4 + j;
                outh[row * NCOLS + col] = f2bf(acc[fm][fn][j] + b);
            }
    }
}

// ---------------------------------------------------------------------------
// valoa_k: [0,340) value-proj (feat native rows); [340,596) off+attn
// (lidar+q_pose native rows, +lidarb); block 596: hist(LDS)+scan+scatter.
// ---------------------------------------------------------------------------
__global__ __launch_bounds__(512) void valoa_k(
    const float* __restrict__ feat, const float* __restrict__ lidar,
    const float* __restrict__ q_pose,
    const unsigned short* __restrict__ wt_val, const unsigned short* __restrict__ wt_oa,
    const float* __restrict__ b_val, const float* __restrict__ b_off,
    const float* __restrict__ b_attn,
    unsigned short* __restrict__ vb, unsigned short* __restrict__ oa,
    unsigned short* __restrict__ lidarb,
    const int* __restrict__ bkt, int* __restrict__ perm)
{
    __shared__ unsigned short As[128 * 32];
    __shared__ unsigned short Bs[384 * 32];
    const int bx = blockIdx.x;
    if (bx < VAL_BLK) {
        gemm_core<256>(As, Bs, bx, feat, nullptr, wt_val, b_val, nullptr, nullptr, vb);
    } else if (bx < VAL_BLK + OA_BLK) {
        gemm_core<384>(As, Bs, bx - VAL_BLK, lidar, q_pose, wt_oa, b_off, b_attn, lidarb, oa);
    } else {
        int* hcnt = (int*)As;           // 512 ints
        int* cur  = ((int*)As) + 512;   // 512 ints
        int* s    = (int*)Bs;           // 512 ints
        const int t = threadIdx.x;
        hcnt[t] = 0;
        __syncthreads();
#pragma unroll 4
        for (int i = 0; i < 64; ++i) atomicAdd(&hcnt[bkt[i * 512 + t]], 1);
        __syncthreads();
        const int v = hcnt[t];
        s[t] = v;
        __syncthreads();
        int acc = v;
#pragma unroll
        for (int o = 1; o < 512; o <<= 1) {
            const int add = (t >= o) ? s[t - o] : 0;
            __syncthreads();
            acc += add;
            s[t] = acc;
            __syncthreads();
        }
        cur[t] = acc - v;
        __syncthreads();
#pragma unroll 4
        for (int i = 0; i < 64; ++i) {
            const int rb = i * 512 + t;
            const int pos = atomicAdd(&cur[bkt[rb]], 1);
            perm[pos] = rb;
        }
    }
}

// ---------------------------------------------------------------------------
// sampler (R12 structure; v/oa now in NATIVE order -> offset math folds the
// (cell*BS+b) interleave, gather loop unchanged).
// ---------------------------------------------------------------------------
__global__ __launch_bounds__(256) void sampler_k(
    const unsigned short* __restrict__ oa,    // [(q*BS+b)][384]: off | aw
    const float* __restrict__ ref2d,          // [MQ][8] (b*NQ+q major)
    const unsigned short* __restrict__ v,     // [(n*BS+b)][256]
    const int* __restrict__ perm,             // [MQ] bucket-sorted rb ids
    unsigned short* __restrict__ outh)        // [MQ][256] nq-major
{
    const int bid = blockIdx.x;
    const int sbid = (bid & 7) * (MQ / 4 / 8) + (bid >> 3);   // XCD swizzle
    const int q0 = sbid * 4;
    const int t = threadIdx.x;

    __shared__ __align__(16) uint2 s_d[4][8][74];  // [tq][h][c*18+lp], padded

#pragma unroll
    for (int it = 0; it < 2; ++it) {     // 512 descriptors, 2 per thread
        const int item = t + it * 256;
        const int tq = item >> 7, hlp = item & 127;
        const int h = hlp >> 4, lp = hlp & 15, li = lp >> 2;
        const int rb = perm[q0 + tq];
        const int b = rb >> 14, qi = rb & (NQ - 1);
        const size_t orow = (size_t)(qi * BS + b) * 384;   // native oa row

        const float2 refv = *(const float2*)(ref2d + (size_t)rb * 8 + li * 2);
        const ushort2 offu = *(const ushort2*)(oa + orow + hlp * 2);
        const float ax = bf2f(oa[orow + 256 + hlp]);

        // softmax over the 16-lane (q,h) group
        float m = ax;
#pragma unroll
        for (int o = 1; o < 16; o <<= 1) m = fmaxf(m, __shfl_xor(m, o));
        const float e = __expf(ax - m);
        float sden = e;
#pragma unroll
        for (int o = 1; o < 16; o <<= 1) sden += __shfl_xor(sden, o);
        const float a = e / sden;

        const int Wl[4]  = {128, 64, 32, 16};
        const int S0l[4] = {0, 16384, 20480, 21504};
        const int Wi = Wl[li]; const float Wf = (float)Wi;
        const float x = (refv.x + bf2f(offu.x) / Wf) * Wf - 0.5f;
        const float y = (refv.y + bf2f(offu.y) / Wf) * Wf - 0.5f;
        const float x0f = floorf(x), y0f = floorf(y);
        const float lx = x - x0f, ly = y - y0f;
        const int x0 = (int)x0f, y0 = (int)y0f;
        const float cw[4] = {(1.f - lx) * (1.f - ly) * a, lx * (1.f - ly) * a,
                             (1.f - lx) * ly * a,          lx * ly * a};
#pragma unroll
        for (int c = 0; c < 4; ++c) {
            const int xi = x0 + (c & 1), yi = y0 + (c >> 1);
            const bool val = (xi >= 0) & (xi < Wi) & (yi >= 0) & (yi < Wi);
            const int xc = min(max(xi, 0), Wi - 1), yc = min(max(yi, 0), Wi - 1);
            const int cell = S0l[li] + yc * Wi + xc;
            const unsigned int ofs = (unsigned int)(cell * BS + b) * 256u + h * 32;  // native v row
            s_d[tq][h][c * 18 + lp] = make_uint2(__float_as_uint(val ? cw[c] : 0.f), ofs);
        }
    }
    __syncthreads();

    const int tq = t >> 6, l = t & 63, h = l >> 3, dq = l & 7;
    const int rb = perm[q0 + tq], b = rb >> 14, qi = rb & (NQ - 1);
    const unsigned short* vd = v + dq * 4;
    const uint2* dp = &s_d[tq][h][0];
    f32x2 acc01 = {0.f, 0.f}, acc23 = {0.f, 0.f};
#pragma unroll
    for (int c = 0; c < 4; ++c) {
#pragma unroll
        for (int i = 0; i < 8; ++i) {
            const uint4 dd = *(const uint4*)(dp + c * 18 + i * 2);  // 2 descriptors
            {
                const uint2 raw = *(const uint2*)(vd + dd.y);
                const float w0 = __uint_as_float(dd.x);
                f32x2 v01; v01.x = __uint_as_float(raw.x << 16);
                           v01.y = __uint_as_float(raw.x & 0xFFFF0000u);
                f32x2 v23; v23.x = __uint_as_float(raw.y << 16);
                           v23.y = __uint_as_float(raw.y & 0xFFFF0000u);
                acc01 += w0 * v01;
                acc23 += w0 * v23;
            }
            {
                const uint2 raw = *(const uint2*)(vd + dd.w);
                const float w1 = __uint_as_float(dd.z);
                f32x2 v01; v01.x = __uint_as_float(raw.x << 16);
                           v01.y = __uint_as_float(raw.x & 0xFFFF0000u);
                f32x2 v23; v23.x = __uint_as_float(raw.y << 16);
                           v23.y = __uint_as_float(raw.y & 0xFFFF0000u);
                acc01 += w1 * v01;
                acc23 += w1 * v23;
            }
        }
    }
    ushort4 o;
    o.x = f2bf(acc01.x); o.y = f2bf(acc01.y);
    o.z = f2bf(acc23.x); o.w = f2bf(acc23.y);
    *(ushort4*)(outh + (size_t)(qi * BS + b) * 256 + h * 32 + dq * 4) = o;
}

// ---------------------------------------------------------------------------
// outproj_k (R12 verbatim): 128-row tile; x = LN1(smp@Wo + b_out + lidarb).
// ---------------------------------------------------------------------------
__global__ __launch_bounds__(512) void outproj_k(
    const unsigned short* __restrict__ smp, const unsigned short* __restrict__ lidarb,
    const unsigned short* __restrict__ Wo, const float* __restrict__ b_out,
    const float* __restrict__ ln1g, const float* __restrict__ ln1b,
    unsigned short* __restrict__ xln)
{
    __shared__ unsigned short As[128 * 32];
    __shared__ unsigned short Bs[256 * 32];
    __shared__ float2 sdLN[128][4];

    const int t = threadIdx.x, l = t & 63, w = t >> 6;
    const int wm = w >> 2, wn = w & 3;
    const int frow = l & 15, fgrp = l >> 4;
    const size_t brow = (size_t)blockIdx.x * 128;

    const int fslot = fgrp ^ ((frow & 3) ^ ((frow >> 2) & 3));
    const int srow = l >> 2;
    const int sswz = (l & 3) ^ ((srow & 3) ^ ((srow >> 2) & 3));

    const unsigned short* gA = smp + (brow + (size_t)(w * 16 + srow)) * 256 + sswz * 8;
    const unsigned short* gB = Wo + ((size_t)(w * 16 + srow)) * 256 + sswz * 8;

    f32x4 acc[4][4];
#pragma unroll
    for (int i = 0; i < 4; ++i)
#pragma unroll
        for (int j = 0; j < 4; ++j) acc[i][j] = f32x4{0.f, 0.f, 0.f, 0.f};

    for (int k0 = 0; k0 < 256; k0 += 32) {
        glds16(gB + k0,         &Bs[w * 512]);
        glds16(gB + 32768 + k0, &Bs[(w + 8) * 512]);
        glds16(gA + k0, &As[w * 512]);
        __syncthreads();

        short8 af[4], bq[4];
#pragma unroll
        for (int fm = 0; fm < 4; ++fm)
            af[fm] = *reinterpret_cast<const short8*>(&As[(wm * 64 + fm * 16 + frow) * 32 + fslot * 8]);
#pragma unroll
        for (int fn = 0; fn < 4; ++fn)
            bq[fn] = *reinterpret_cast<const short8*>(&Bs[(wn * 64 + fn * 16 + frow) * 32 + fslot * 8]);
#pragma unroll
        for (int fm = 0; fm < 4; ++fm)
#pragma unroll
            for (int fn = 0; fn < 4; ++fn)
                acc[fm][fn] = __builtin_amdgcn_mfma_f32_16x16x32_bf16(af[fm], bq[fn], acc[fm][fn], 0, 0, 0);
        __syncthreads();
    }

    int cols[4];
#pragma unroll
    for (int fn = 0; fn < 4; ++fn) cols[fn] = wn * 64 + fn * 16 + frow;

#pragma unroll
    for (int fm = 0; fm < 4; ++fm)
#pragma unroll
        for (int j = 0; j < 4; ++j) {
            const size_t row = brow + wm * 64 + fm * 16 + fgrp * 4 + j;
#pragma unroll
            for (int fn = 0; fn < 4; ++fn)
                acc[fm][fn][j] += b_out[cols[fn]] + bf2f(lidarb[row * 256 + cols[fn]]);
        }

#pragma unroll
    for (int fm = 0; fm < 4; ++fm)
#pragma unroll
        for (int j = 0; j < 4; ++j) {
            float s1 = 0.f, s2 = 0.f;
#pragma unroll
            for (int fn = 0; fn < 4; ++fn) { const float x = acc[fm][fn][j]; s1 += x; s2 += x * x; }
#pragma unroll
            for (int o = 1; o < 16; o <<= 1) { s1 += __shfl_xor(s1, o); s2 += __shfl_xor(s2, o); }
            if (frow == 0)
                sdLN[wm * 64 + fm * 16 + fgrp * 4 + j][wn] = make_float2(s1, s2);
        }
    __syncthreads();
    float gv[4], bv[4];
#pragma unroll
    for (int fn = 0; fn < 4; ++fn) { gv[fn] = ln1g[cols[fn]]; bv[fn] = ln1b[cols[fn]]; }
#pragma unroll
    for (int fm = 0; fm < 4; ++fm)
#pragma unroll
        for (int j = 0; j < 4; ++j) {
            const int rl = wm * 64 + fm * 16 + fgrp * 4 + j;
            const float2 p0 = sdLN[rl][0], p1 = sdLN[rl][1], p2 = sdLN[rl][2], p3 = sdLN[rl][3];
            const float s1 = p0.x + p1.x + p2.x + p3.x;
            const float s2 = p0.y + p1.y + p2.y + p3.y;
            const float mu = s1 * (1.f / 256.f);
            const float var = s2 * (1.f / 256.f) - mu * mu;
            const float rstd = rsqrtf(var + 1e-5f);
            const size_t row = brow + rl;
#pragma unroll
            for (int fn = 0; fn < 4; ++fn)
                xln[row * 256 + cols[fn]] = f2bf((acc[fm][fn][j] - mu) * rstd * gv[fn] + bv[fn]);
        }
}

// ---------------------------------------------------------------------------
// ffn_fused (R12 verbatim): h = relu(X@W1); out = LN2(h@W2 + X), f32 out.
// ---------------------------------------------------------------------------
__global__ __launch_bounds__(512) void ffn_fused(
    const unsigned short* __restrict__ X,
    const unsigned short* __restrict__ W1t, const unsigned short* __restrict__ W2t,
    const float* __restrict__ lng, const float* __restrict__ lnb,
    float* __restrict__ outf)
{
    __shared__ unsigned short As[64 * 32];
    __shared__ unsigned short Bs[256 * 32];
    __shared__ unsigned short Hs[64 * 256];
    __shared__ float2 sdLN[64][4];

    const int t = threadIdx.x, l = t & 63, w = t >> 6;
    const int wm = w >> 2, wn = w & 3;
    const int frow = l & 15, fgrp = l >> 4;
    const size_t brow = (size_t)blockIdx.x * 64;

    const int fslot = fgrp ^ ((frow & 3) ^ ((frow >> 2) & 3));
    const int srow = l >> 2;
    const int sswz = (l & 3) ^ ((srow & 3) ^ ((srow >> 2) & 3));

    const unsigned short* gX  = X + (brow + (size_t)((w & 3) * 16 + srow)) * 256 + sswz * 8;
    const unsigned short* gW1 = W1t + ((size_t)(w * 16 + srow)) * 256 + sswz * 8;
    const unsigned short* gW2 = W2t + ((size_t)(w * 16 + srow)) * 256 + sswz * 8;

    f32x4 acc[2][4];

#pragma unroll
    for (int i = 0; i < 2; ++i)
#pragma unroll
        for (int j = 0; j < 4; ++j) acc[i][j] = f32x4{0.f, 0.f, 0.f, 0.f};

    for (int k0 = 0; k0 < 256; k0 += 32) {
        glds16(gW1 + k0,         &Bs[w * 512]);
        glds16(gW1 + 32768 + k0, &Bs[(w + 8) * 512]);
        if (w < 4) glds16(gX + k0, &As[w * 512]);
        __syncthreads();

        short8 af[2], bq[4];
#pragma unroll
        for (int fm = 0; fm < 2; ++fm)
            af[fm] = *reinterpret_cast<const short8*>(&As[(wm * 32 + fm * 16 + frow) * 32 + fslot * 8]);
#pragma unroll
        for (int fn = 0; fn < 4; ++fn)
            bq[fn] = *reinterpret_cast<const short8*>(&Bs[(wn * 64 + fn * 16 + frow) * 32 + fslot * 8]);
#pragma unroll
        for (int fm = 0; fm < 2; ++fm)
#pragma unroll
            for (int fn = 0; fn < 4; ++fn)
                acc[fm][fn] = __builtin_amdgcn_mfma_f32_16x16x32_bf16(af[fm], bq[fn], acc[fm][fn], 0, 0, 0);
        __syncthreads();
    }

#pragma unroll
    for (int fm = 0; fm < 2; ++fm)
#pragma unroll
        for (int fn = 0; fn < 4; ++fn) {
            const int col = wn * 64 + fn * 16 + frow;
#pragma unroll
            for (int j = 0; j < 4; ++j) {
                const int row = wm * 32 + fm * 16 + fgrp * 4 + j;
                const int ss = (col >> 3) ^ (row & 7);
                Hs[row * 256 + ss * 8 + (col & 7)] = f2bf(fmaxf(acc[fm][fn][j], 0.f));
            }
        }
    __syncthreads();

#pragma unroll
    for (int i = 0; i < 2; ++i)
#pragma unroll
        for (int j = 0; j < 4; ++j) acc[i][j] = f32x4{0.f, 0.f, 0.f, 0.f};

    for (int k0 = 0; k0 < 256; k0 += 32) {
        glds16(gW2 + k0,         &Bs[w * 512]);
        glds16(gW2 + 32768 + k0, &Bs[(w + 8) * 512]);
        __syncthreads();

        short8 af[2], bq[4];
#pragma unroll
        for (int fm = 0; fm < 2; ++fm) {
            const int row = wm * 32 + fm * 16 + frow;
            const int ksg = (k0 >> 3) + fgrp;
            const int ss = ksg ^ (row & 7);
            af[fm] = *reinterpret_cast<const short8*>(&Hs[row * 256 + ss * 8]);
        }
#pragma unroll
        for (int fn = 0; fn < 4; ++fn)
            bq[fn] = *reinterpret_cast<const short8*>(&Bs[(wn * 64 + fn * 16 + frow) * 32 + fslot * 8]);
#pragma unroll
        for (int fm = 0; fm < 2; ++fm)
#pragma unroll
            for (int fn = 0; fn < 4; ++fn)
                acc[fm][fn] = __builtin_amdgcn_mfma_f32_16x16x32_bf16(af[fm], bq[fn], acc[fm][fn], 0, 0, 0);
        __syncthreads();
    }

#pragma unroll
    for (int fm = 0; fm < 2; ++fm)
#pragma unroll
        for (int fn = 0; fn < 4; ++fn) {
            const int col = wn * 64 + fn * 16 + frow;
#pragma unroll
            for (int j = 0; j < 4; ++j) {
                const size_t row = brow + wm * 32 + fm * 16 + fgrp * 4 + j;
                acc[fm][fn][j] += bf2f(X[row * 256 + col]);
            }
        }
#pragma unroll
    for (int fm = 0; fm < 2; ++fm)
#pragma unroll
        for (int j = 0; j < 4; ++j) {
            float s1 = 0.f, s2 = 0.f;
#pragma unroll
            for (int fn = 0; fn < 4; ++fn) { const float x = acc[fm][fn][j]; s1 += x; s2 += x * x; }
#pragma unroll
            for (int o = 1; o < 16; o <<= 1) { s1 += __shfl_xor(s1, o); s2 += __shfl_xor(s2, o); }
            if (frow == 0)
                sdLN[wm * 32 + fm * 16 + fgrp * 4 + j][wn] = make_float2(s1, s2);
        }
    __syncthreads();
#pragma unroll
    for (int fm = 0; fm < 2; ++fm)
#pragma unroll
        for (int j = 0; j < 4; ++j) {
            const int rl = wm * 32 + fm * 16 + fgrp * 4 + j;
            const float2 p0 = sdLN[rl][0], p1 = sdLN[rl][1], p2 = sdLN[rl][2], p3 = sdLN[rl][3];
            const float s1 = p0.x + p1.x + p2.x + p3.x;
            const float s2 = p0.y + p1.y + p2.y + p3.y;
            const float mu = s1 * (1.f / 256.f);
            const float var = s2 * (1.f / 256.f) - mu * mu;
            const float rstd = rsqrtf(var + 1e-5f);
            const size_t row = brow + rl;
#pragma unroll
            for (int fn = 0; fn < 4; ++fn) {
                const int col = wn * 64 + fn * 16 + frow;
                outf[row * 256 + col] = (acc[fm][fn][j] - mu) * rstd * lng[col] + lnb[col];
            }
        }
}

// ---------------------------------------------------------------------------
extern "C" void kernel_launch(void* const* d_in, const int* in_sizes, int n_in,
                              void* d_out, int out_size, void* d_ws, size_t ws_size,
                              hipStream_t stream)
{
    const float* lidar  = (const float*)d_in[0];
    const float* feat   = (const float*)d_in[1];
    const float* ref2d  = (const float*)d_in[2];
    const float* q_pose = (const float*)d_in[5];
    const float* W_off  = (const float*)d_in[6];
    const float* b_off  = (const float*)d_in[7];
    const float* W_attn = (const float*)d_in[8];
    const float* b_attn = (const float*)d_in[9];
    const float* W_val  = (const float*)d_in[10];
    const float* b_val  = (const float*)d_in[11];
    const float* W_out  = (const float*)d_in[12];
    const float* b_out  = (const float*)d_in[13];
    const float* ln1_g  = (const float*)d_in[14];
    const float* ln1_b  = (const float*)d_in[15];
    const float* ffn_w1 = (const float*)d_in[16];
    const float* ffn_w2 = (const float*)d_in[17];
    const float* ln2_g  = (const float*)d_in[18];
    const float* ln2_b  = (const float*)d_in[19];

    float* out = (float*)d_out;
    char*  ws  = (char*)d_ws;

    // byte offsets; high-water ~98.8 MB
    unsigned short* vb     = (unsigned short*)(ws + 0);          // 22,282,240
    unsigned short* oa     = (unsigned short*)(ws + 22282240);   // 25,165,824
    unsigned short* smp    = (unsigned short*)(ws + 47448064);   // 16,777,216
    unsigned short* xln    = (unsigned short*)(ws + 64225280);   // 16,777,216
    unsigned short* lidarb = (unsigned short*)(ws + 81002496);   // 16,777,216
    unsigned short* wt     = (unsigned short*)(ws + 97779712);   //    720,896
    int* perm = (int*)(ws + 98500608);                           //    131,072
    int* bkt  = (int*)(ws + 98631680);                           //    131,072
    unsigned short* wt_val = wt;
    unsigned short* wt_oa  = wt + 65536;          // [384][256]
    unsigned short* wt_out = wt + 163840;
    unsigned short* wt_f1  = wt + 229376;
    unsigned short* wt_f2  = wt + 294912;

    WtArgs wa;
    wa.src[0] = W_val;  wa.dst[0] = wt_val;          wa.n[0] = 256;
    wa.src[1] = W_off;  wa.dst[1] = wt_oa;           wa.n[1] = 256;
    wa.src[2] = W_attn; wa.dst[2] = wt_oa + 65536;   wa.n[2] = 128;
    wa.src[3] = W_out;  wa.dst[3] = wt_out;          wa.n[3] = 256;
    wa.src[4] = ffn_w1; wa.dst[4] = wt_f1;           wa.n[4] = 256;
    wa.src[5] = ffn_w2; wa.dst[5] = wt_f2;           wa.n[5] = 256;

    // 1. weight transpose + bucket ids
    prep_wt<<<dim3(384, 7), dim3(256), 0, stream>>>(wa, ref2d, bkt);

    // 2. value-proj + off/attn-proj (native order, sequential reads)
    //    + lidarb copy + hist/scan/scatter block
    valoa_k<<<dim3(VAL_BLK + OA_BLK + 1), dim3(512), 0, stream>>>(
        feat, lidar, q_pose, wt_val, wt_oa, b_val, b_off, b_attn,
        vb, oa, lidarb, bkt, perm);

    // 3. deformable sampling (+softmax), sorted order -> smp bf16 nq-major
    sampler_k<<<dim3(MQ / 4), dim3(256), 0, stream>>>(oa, ref2d, vb, perm, smp);

    // 4. out-proj + LN1 -> xln bf16
    outproj_k<<<dim3(MQ / 128), dim3(512), 0, stream>>>(
        smp, lidarb, wt_out, b_out, ln1_g, ln1_b, xln);

    // 5. FFN1+FFN2+LN2 -> d_out f32
    ffn_fused<<<dim3(MQ / 64), dim3(512), 0, stream>>>(
        xln, wt_f1, wt_f2, ln2_g, ln2_b, out);
}

// Round 16
// 195.582 us; speedup vs baseline: 1.0836x; 1.0101x over previous
//
#include <hip/hip_runtime.h>
#include <cstdint>

#define EMBED 256
#define HEADS 8
#define LEVELS 4
#define POINTS 4
#define BS 2
#define NQ 16384
#define NV 21760          // 128*128+64*64+32*32+16*16
#define MQ (BS*NQ)        // 32768
#define MV (BS*NV)        // 43520
#define VAL_BLK 340       // MV/128
#define OA_BLK  256       // MQ/128

typedef __attribute__((ext_vector_type(8))) short short8;
typedef __attribute__((ext_vector_type(4))) float f32x4;
typedef __attribute__((ext_vector_type(2))) float f32x2;

__device__ __forceinline__ unsigned short f2bf(float f) {
    unsigned int u = __float_as_uint(f);
    u = (u + 0x7FFFu + ((u >> 16) & 1u)) >> 16;   // RNE
    return (unsigned short)u;
}
__device__ __forceinline__ float bf2f(unsigned short h) {
    return __uint_as_float(((unsigned int)h) << 16);
}
__device__ __forceinline__ void glds16(const unsigned short* g, unsigned short* l) {
    __builtin_amdgcn_global_load_lds((const __attribute__((address_space(1))) void*)g,
                                     (__attribute__((address_space(3))) void*)l, 16, 0, 0);
}

// ---------------------------------------------------------------------------
// prep_wt: y<6 -> Wt[n][k] = bf16(W[k][n]); y==6 -> bucket ids + GLOBAL hist
// atomics (distributed; hist zeroed by hipMemsetAsync).
// ---------------------------------------------------------------------------
struct WtArgs {
    const float* src[6];
    unsigned short* dst[6];
    int n[6];
};
__global__ __launch_bounds__(256) void prep_wt(
    WtArgs a, const float* __restrict__ ref2d,
    int* __restrict__ bkt, int* __restrict__ hist)
{
    const int t = threadIdx.x, g = blockIdx.y, bx = blockIdx.x;
    if (g == 6) {
        if (bx < 64) {
#pragma unroll
            for (int i = 0; i < 2; ++i) {
                const int rb = bx * 512 + i * 256 + t;
                const float x = ref2d[(size_t)rb * 8 + 0];
                const float y = ref2d[(size_t)rb * 8 + 1];
                const int qx = min(15, max(0, (int)(x * 16.f)));
                const int qy = min(15, max(0, (int)(y * 16.f)));
                const int bv = (rb >> 14) * 256 + qy * 16 + qx;
                bkt[rb] = bv;
                atomicAdd(&hist[bv], 1);
            }
        }
        return;
    }
    const int N = a.n[g];
    const int e = bx * 256 + t;
    if (e >= 256 * N) return;
    const int k = e / N, n = e - k * N;
    a.dst[g][(size_t)n * 256 + k] = f2bf(a.src[g][e]);
}

// ---------------------------------------------------------------------------
// gemm_core: SOURCE-ORDER rows (sequential HBM reads), R15 verbatim.
// ---------------------------------------------------------------------------
template<int NCOLS>
__device__ __forceinline__ void gemm_core(
    unsigned short* As, unsigned short* Bs, int bx,
    const float* __restrict__ Af, const float* __restrict__ A2f,
    const unsigned short* __restrict__ Bt,
    const float* __restrict__ bias0, const float* __restrict__ bias1,
    unsigned short* __restrict__ lidarb, unsigned short* __restrict__ outh)
{
    constexpr int FN = NCOLS / 64;
    const int t = threadIdx.x, l = t & 63, w = t >> 6;
    const int wm = w >> 2, wn = w & 3;
    const int frow = l & 15, fgrp = l >> 4;
    const size_t brow = (size_t)bx * 128;

    const int fslot = fgrp ^ ((frow & 3) ^ ((frow >> 2) & 3));
    const int srow = l >> 2;
    const int sswz = (l & 3) ^ ((srow & 3) ^ ((srow >> 2) & 3));
    const unsigned short* gB0 = Bt + ((size_t)(w * 16 + srow)) * 256 + sswz * 8;

    const int arow_s = t >> 2, aslot_s = t & 3;
    const size_t srcrow = (brow + arow_s) * 256;     // NATIVE row -> sequential
    const float* srcA = Af + srcrow;
    const float* srcA2 = A2f ? A2f + srcrow : nullptr;
    const int aswz_s = aslot_s ^ ((arow_s & 3) ^ ((arow_s >> 2) & 3));

    f32x4 acc[4][FN];
#pragma unroll
    for (int i = 0; i < 4; ++i)
#pragma unroll
        for (int j = 0; j < FN; ++j) acc[i][j] = f32x4{0.f, 0.f, 0.f, 0.f};

    float4 pA0 = *(const float4*)(srcA + aslot_s * 8);
    float4 pA1 = *(const float4*)(srcA + aslot_s * 8 + 4);
    float4 pC0, pC1;
    if (srcA2) { pC0 = *(const float4*)(srcA2 + aslot_s * 8);
                 pC1 = *(const float4*)(srcA2 + aslot_s * 8 + 4); }

    for (int k0 = 0; k0 < 256; k0 += 32) {
        glds16(gB0 + k0,         &Bs[w * 512]);
        glds16(gB0 + 32768 + k0, &Bs[(w + 8) * 512]);
        if constexpr (NCOLS == 384)
            glds16(gB0 + 65536 + k0, &Bs[(w + 16) * 512]);

        if (lidarb) {   // bf16(lidar) side-copy, native order
            short8 lk;
            lk[0] = (short)f2bf(pA0.x); lk[1] = (short)f2bf(pA0.y);
            lk[2] = (short)f2bf(pA0.z); lk[3] = (short)f2bf(pA0.w);
            lk[4] = (short)f2bf(pA1.x); lk[5] = (short)f2bf(pA1.y);
            lk[6] = (short)f2bf(pA1.z); lk[7] = (short)f2bf(pA1.w);
            *reinterpret_cast<short8*>(lidarb + srcrow + k0 + aslot_s * 8) = lk;
        }

        float c[8] = {pA0.x, pA0.y, pA0.z, pA0.w, pA1.x, pA1.y, pA1.z, pA1.w};
        if (srcA2) {
            c[0] += pC0.x; c[1] += pC0.y; c[2] += pC0.z; c[3] += pC0.w;
            c[4] += pC1.x; c[5] += pC1.y; c[6] += pC1.z; c[7] += pC1.w;
        }
        short8 pk;
#pragma unroll
        for (int i = 0; i < 8; ++i) pk[i] = (short)f2bf(c[i]);
        *reinterpret_cast<short8*>(&As[arow_s * 32 + aswz_s * 8]) = pk;
        if (k0 + 32 < 256) {
            pA0 = *(const float4*)(srcA + k0 + 32 + aslot_s * 8);
            pA1 = *(const float4*)(srcA + k0 + 32 + aslot_s * 8 + 4);
            if (srcA2) { pC0 = *(const float4*)(srcA2 + k0 + 32 + aslot_s * 8);
                         pC1 = *(const float4*)(srcA2 + k0 + 32 + aslot_s * 8 + 4); }
        }
        __syncthreads();

        short8 af[4]; short8 bq[FN];
#pragma unroll
        for (int fm = 0; fm < 4; ++fm)
            af[fm] = *reinterpret_cast<const short8*>(&As[(wm * 64 + fm * 16 + frow) * 32 + fslot * 8]);
#pragma unroll
        for (int fn = 0; fn < FN; ++fn)
            bq[fn] = *reinterpret_cast<const short8*>(&Bs[(wn * (NCOLS / 4) + fn * 16 + frow) * 32 + fslot * 8]);
#pragma unroll
        for (int fm = 0; fm < 4; ++fm)
#pragma unroll
            for (int fn = 0; fn < FN; ++fn)
                acc[fm][fn] = __builtin_amdgcn_mfma_f32_16x16x32_bf16(af[fm], bq[fn], acc[fm][fn], 0, 0, 0);
        __syncthreads();
    }

#pragma unroll
    for (int fn = 0; fn < FN; ++fn) {
        const int col = wn * (NCOLS / 4) + fn * 16 + frow;
        float b;
        if (NCOLS == 384) b = (col < 256) ? bias0[col] : bias1[col - 256];
        else              b = bias0[col];
#pragma unroll
        for (int fm = 0; fm < 4; ++fm)
#pragma unroll
            for (int j = 0; j < 4; ++j) {
                const size_t row = brow + wm * 64 + fm * 16 + fgrp * 4 + j;
                outh[row * NCOLS + col] = f2bf(acc[fm][fn][j] + b);
            }
    }
}

// ---------------------------------------------------------------------------
// valoa_k: [0,340) value-proj; [340,596) off+attn (+lidarb); block 596:
// SCAN ONLY -> gcur (exclusive prefix in global). No atomic loops here.
// ---------------------------------------------------------------------------
__global__ __launch_bounds__(512) void valoa_k(
    const float* __restrict__ feat, const float* __restrict__ lidar,
    const float* __restrict__ q_pose,
    const unsigned short* __restrict__ wt_val, const unsigned short* __restrict__ wt_oa,
    const float* __restrict__ b_val, const float* __restrict__ b_off,
    const float* __restrict__ b_attn,
    unsigned short* __restrict__ vb, unsigned short* __restrict__ oa,
    unsigned short* __restrict__ lidarb,
    const int* __restrict__ hist, int* __restrict__ gcur)
{
    __shared__ unsigned short As[128 * 32];
    __shared__ unsigned short Bs[384 * 32];
    const int bx = blockIdx.x;
    if (bx < VAL_BLK) {
        gemm_core<256>(As, Bs, bx, feat, nullptr, wt_val, b_val, nullptr, nullptr, vb);
    } else if (bx < VAL_BLK + OA_BLK) {
        gemm_core<384>(As, Bs, bx - VAL_BLK, lidar, q_pose, wt_oa, b_off, b_attn, lidarb, oa);
    } else {
        int* s = (int*)As;
        const int t = threadIdx.x;
        const int v = hist[t];
        s[t] = v;
        __syncthreads();
        int acc = v;
#pragma unroll
        for (int o = 1; o < 512; o <<= 1) {
            const int add = (t >= o) ? s[t - o] : 0;
            __syncthreads();
            acc += add;
            s[t] = acc;
            __syncthreads();
        }
        gcur[t] = acc - v;   // exclusive prefix -> global cursor
    }
}

// ---------------------------------------------------------------------------
// scatter_k: distributed scatter via GLOBAL atomics (64 blocks x 512 thr).
// ---------------------------------------------------------------------------
__global__ __launch_bounds__(512) void scatter_k(
    const int* __restrict__ bkt, int* __restrict__ gcur, int* __restrict__ perm)
{
    const int rb = blockIdx.x * 512 + threadIdx.x;
    const int pos = atomicAdd(&gcur[bkt[rb]], 1);
    perm[pos] = rb;
}

// ---------------------------------------------------------------------------
// sampler (R15 verbatim): native-order v/oa, paired ds_read_b128 descriptors,
// f32x2 pk-fma. 4 q/block, 256 thr.
// ---------------------------------------------------------------------------
__global__ __launch_bounds__(256) void sampler_k(
    const unsigned short* __restrict__ oa,    // [(q*BS+b)][384]: off | aw
    const float* __restrict__ ref2d,          // [MQ][8] (b*NQ+q major)
    const unsigned short* __restrict__ v,     // [(n*BS+b)][256]
    const int* __restrict__ perm,             // [MQ] bucket-sorted rb ids
    unsigned short* __restrict__ outh)        // [MQ][256] nq-major
{
    const int bid = blockIdx.x;
    const int sbid = (bid & 7) * (MQ / 4 / 8) + (bid >> 3);   // XCD swizzle
    const int q0 = sbid * 4;
    const int t = threadIdx.x;

    __shared__ __align__(16) uint2 s_d[4][8][74];  // [tq][h][c*18+lp], padded

#pragma unroll
    for (int it = 0; it < 2; ++it) {     // 512 descriptors, 2 per thread
        const int item = t + it * 256;
        const int tq = item >> 7, hlp = item & 127;
        const int h = hlp >> 4, lp = hlp & 15, li = lp >> 2;
        const int rb = perm[q0 + tq];
        const int b = rb >> 14, qi = rb & (NQ - 1);
        const size_t orow = (size_t)(qi * BS + b) * 384;   // native oa row

        const float2 refv = *(const float2*)(ref2d + (size_t)rb * 8 + li * 2);
        const ushort2 offu = *(const ushort2*)(oa + orow + hlp * 2);
        const float ax = bf2f(oa[orow + 256 + hlp]);

        // softmax over the 16-lane (q,h) group
        float m = ax;
#pragma unroll
        for (int o = 1; o < 16; o <<= 1) m = fmaxf(m, __shfl_xor(m, o));
        const float e = __expf(ax - m);
        float sden = e;
#pragma unroll
        for (int o = 1; o < 16; o <<= 1) sden += __shfl_xor(sden, o);
        const float a = e / sden;

        const int Wl[4]  = {128, 64, 32, 16};
        const int S0l[4] = {0, 16384, 20480, 21504};
        const int Wi = Wl[li]; const float Wf = (float)Wi;
        const float x = (refv.x + bf2f(offu.x) / Wf) * Wf - 0.5f;
        const float y = (refv.y + bf2f(offu.y) / Wf) * Wf - 0.5f;
        const float x0f = floorf(x), y0f = floorf(y);
        const float lx = x - x0f, ly = y - y0f;
        const int x0 = (int)x0f, y0 = (int)y0f;
        const float cw[4] = {(1.f - lx) * (1.f - ly) * a, lx * (1.f - ly) * a,
                             (1.f - lx) * ly * a,          lx * ly * a};
#pragma unroll
        for (int c = 0; c < 4; ++c) {
            const int xi = x0 + (c & 1), yi = y0 + (c >> 1);
            const bool val = (xi >= 0) & (xi < Wi) & (yi >= 0) & (yi < Wi);
            const int xc = min(max(xi, 0), Wi - 1), yc = min(max(yi, 0), Wi - 1);
            const int cell = S0l[li] + yc * Wi + xc;
            const unsigned int ofs = (unsigned int)(cell * BS + b) * 256u + h * 32;  // native v row
            s_d[tq][h][c * 18 + lp] = make_uint2(__float_as_uint(val ? cw[c] : 0.f), ofs);
        }
    }
    __syncthreads();

    const int tq = t >> 6, l = t & 63, h = l >> 3, dq = l & 7;
    const int rb = perm[q0 + tq], b = rb >> 14, qi = rb & (NQ - 1);
    const unsigned short* vd = v + dq * 4;
    const uint2* dp = &s_d[tq][h][0];
    f32x2 acc01 = {0.f, 0.f}, acc23 = {0.f, 0.f};
#pragma unroll
    for (int c = 0; c < 4; ++c) {
#pragma unroll
        for (int i = 0; i < 8; ++i) {
            const uint4 dd = *(const uint4*)(dp + c * 18 + i * 2);  // 2 descriptors
            {
                const uint2 raw = *(const uint2*)(vd + dd.y);
                const float w0 = __uint_as_float(dd.x);
                f32x2 v01; v01.x = __uint_as_float(raw.x << 16);
                           v01.y = __uint_as_float(raw.x & 0xFFFF0000u);
                f32x2 v23; v23.x = __uint_as_float(raw.y << 16);
                           v23.y = __uint_as_float(raw.y & 0xFFFF0000u);
                acc01 += w0 * v01;
                acc23 += w0 * v23;
            }
            {
                const uint2 raw = *(const uint2*)(vd + dd.w);
                const float w1 = __uint_as_float(dd.z);
                f32x2 v01; v01.x = __uint_as_float(raw.x << 16);
                           v01.y = __uint_as_float(raw.x & 0xFFFF0000u);
                f32x2 v23; v23.x = __uint_as_float(raw.y << 16);
                           v23.y = __uint_as_float(raw.y & 0xFFFF0000u);
                acc01 += w1 * v01;
                acc23 += w1 * v23;
            }
        }
    }
    ushort4 o;
    o.x = f2bf(acc01.x); o.y = f2bf(acc01.y);
    o.z = f2bf(acc23.x); o.w = f2bf(acc23.y);
    *(ushort4*)(outh + (size_t)(qi * BS + b) * 256 + h * 32 + dq * 4) = o;
}

// ---------------------------------------------------------------------------
// outproj_k (R15 verbatim): 128-row tile; x = LN1(smp@Wo + b_out + lidarb).
// ---------------------------------------------------------------------------
__global__ __launch_bounds__(512) void outproj_k(
    const unsigned short* __restrict__ smp, const unsigned short* __restrict__ lidarb,
    const unsigned short* __restrict__ Wo, const float* __restrict__ b_out,
    const float* __restrict__ ln1g, const float* __restrict__ ln1b,
    unsigned short* __restrict__ xln)
{
    __shared__ unsigned short As[128 * 32];
    __shared__ unsigned short Bs[256 * 32];
    __shared__ float2 sdLN[128][4];

    const int t = threadIdx.x, l = t & 63, w = t >> 6;
    const int wm = w >> 2, wn = w & 3;
    const int frow = l & 15, fgrp = l >> 4;
    const size_t brow = (size_t)blockIdx.x * 128;

    const int fslot = fgrp ^ ((frow & 3) ^ ((frow >> 2) & 3));
    const int srow = l >> 2;
    const int sswz = (l & 3) ^ ((srow & 3) ^ ((srow >> 2) & 3));

    const unsigned short* gA = smp + (brow + (size_t)(w * 16 + srow)) * 256 + sswz * 8;
    const unsigned short* gB = Wo + ((size_t)(w * 16 + srow)) * 256 + sswz * 8;

    f32x4 acc[4][4];
#pragma unroll
    for (int i = 0; i < 4; ++i)
#pragma unroll
        for (int j = 0; j < 4; ++j) acc[i][j] = f32x4{0.f, 0.f, 0.f, 0.f};

    for (int k0 = 0; k0 < 256; k0 += 32) {
        glds16(gB + k0,         &Bs[w * 512]);
        glds16(gB + 32768 + k0, &Bs[(w + 8) * 512]);
        glds16(gA + k0, &As[w * 512]);
        __syncthreads();

        short8 af[4], bq[4];
#pragma unroll
        for (int fm = 0; fm < 4; ++fm)
            af[fm] = *reinterpret_cast<const short8*>(&As[(wm * 64 + fm * 16 + frow) * 32 + fslot * 8]);
#pragma unroll
        for (int fn = 0; fn < 4; ++fn)
            bq[fn] = *reinterpret_cast<const short8*>(&Bs[(wn * 64 + fn * 16 + frow) * 32 + fslot * 8]);
#pragma unroll
        for (int fm = 0; fm < 4; ++fm)
#pragma unroll
            for (int fn = 0; fn < 4; ++fn)
                acc[fm][fn] = __builtin_amdgcn_mfma_f32_16x16x32_bf16(af[fm], bq[fn], acc[fm][fn], 0, 0, 0);
        __syncthreads();
    }

    int cols[4];
#pragma unroll
    for (int fn = 0; fn < 4; ++fn) cols[fn] = wn * 64 + fn * 16 + frow;

#pragma unroll
    for (int fm = 0; fm < 4; ++fm)
#pragma unroll
        for (int j = 0; j < 4; ++j) {
            const size_t row = brow + wm * 64 + fm * 16 + fgrp * 4 + j;
#pragma unroll
            for (int fn = 0; fn < 4; ++fn)
                acc[fm][fn][j] += b_out[cols[fn]] + bf2f(lidarb[row * 256 + cols[fn]]);
        }

#pragma unroll
    for (int fm = 0; fm < 4; ++fm)
#pragma unroll
        for (int j = 0; j < 4; ++j) {
            float s1 = 0.f, s2 = 0.f;
#pragma unroll
            for (int fn = 0; fn < 4; ++fn) { const float x = acc[fm][fn][j]; s1 += x; s2 += x * x; }
#pragma unroll
            for (int o = 1; o < 16; o <<= 1) { s1 += __shfl_xor(s1, o); s2 += __shfl_xor(s2, o); }
            if (frow == 0)
                sdLN[wm * 64 + fm * 16 + fgrp * 4 + j][wn] = make_float2(s1, s2);
        }
    __syncthreads();
    float gv[4], bv[4];
#pragma unroll
    for (int fn = 0; fn < 4; ++fn) { gv[fn] = ln1g[cols[fn]]; bv[fn] = ln1b[cols[fn]]; }
#pragma unroll
    for (int fm = 0; fm < 4; ++fm)
#pragma unroll
        for (int j = 0; j < 4; ++j) {
            const int rl = wm * 64 + fm * 16 + fgrp * 4 + j;
            const float2 p0 = sdLN[rl][0], p1 = sdLN[rl][1], p2 = sdLN[rl][2], p3 = sdLN[rl][3];
            const float s1 = p0.x + p1.x + p2.x + p3.x;
            const float s2 = p0.y + p1.y + p2.y + p3.y;
            const float mu = s1 * (1.f / 256.f);
            const float var = s2 * (1.f / 256.f) - mu * mu;
            const float rstd = rsqrtf(var + 1e-5f);
            const size_t row = brow + rl;
#pragma unroll
            for (int fn = 0; fn < 4; ++fn)
                xln[row * 256 + cols[fn]] = f2bf((acc[fm][fn][j] - mu) * rstd * gv[fn] + bv[fn]);
        }
}

// ---------------------------------------------------------------------------
// ffn_fused (R15 verbatim): h = relu(X@W1); out = LN2(h@W2 + X), f32 out.
// ---------------------------------------------------------------------------
__global__ __launch_bounds__(512) void ffn_fused(
    const unsigned short* __restrict__ X,
    const unsigned short* __restrict__ W1t, const unsigned short* __restrict__ W2t,
    const float* __restrict__ lng, const float* __restrict__ lnb,
    float* __restrict__ outf)
{
    __shared__ unsigned short As[64 * 32];
    __shared__ unsigned short Bs[256 * 32];
    __shared__ unsigned short Hs[64 * 256];
    __shared__ float2 sdLN[64][4];

    const int t = threadIdx.x, l = t & 63, w = t >> 6;
    const int wm = w >> 2, wn = w & 3;
    const int frow = l & 15, fgrp = l >> 4;
    const size_t brow = (size_t)blockIdx.x * 64;

    const int fslot = fgrp ^ ((frow & 3) ^ ((frow >> 2) & 3));
    const int srow = l >> 2;
    const int sswz = (l & 3) ^ ((srow & 3) ^ ((srow >> 2) & 3));

    const unsigned short* gX  = X + (brow + (size_t)((w & 3) * 16 + srow)) * 256 + sswz * 8;
    const unsigned short* gW1 = W1t + ((size_t)(w * 16 + srow)) * 256 + sswz * 8;
    const unsigned short* gW2 = W2t + ((size_t)(w * 16 + srow)) * 256 + sswz * 8;

    f32x4 acc[2][4];

#pragma unroll
    for (int i = 0; i < 2; ++i)
#pragma unroll
        for (int j = 0; j < 4; ++j) acc[i][j] = f32x4{0.f, 0.f, 0.f, 0.f};

    for (int k0 = 0; k0 < 256; k0 += 32) {
        glds16(gW1 + k0,         &Bs[w * 512]);
        glds16(gW1 + 32768 + k0, &Bs[(w + 8) * 512]);
        if (w < 4) glds16(gX + k0, &As[w * 512]);
        __syncthreads();

        short8 af[2], bq[4];
#pragma unroll
        for (int fm = 0; fm < 2; ++fm)
            af[fm] = *reinterpret_cast<const short8*>(&As[(wm * 32 + fm * 16 + frow) * 32 + fslot * 8]);
#pragma unroll
        for (int fn = 0; fn < 4; ++fn)
            bq[fn] = *reinterpret_cast<const short8*>(&Bs[(wn * 64 + fn * 16 + frow) * 32 + fslot * 8]);
#pragma unroll
        for (int fm = 0; fm < 2; ++fm)
#pragma unroll
            for (int fn = 0; fn < 4; ++fn)
                acc[fm][fn] = __builtin_amdgcn_mfma_f32_16x16x32_bf16(af[fm], bq[fn], acc[fm][fn], 0, 0, 0);
        __syncthreads();
    }

#pragma unroll
    for (int fm = 0; fm < 2; ++fm)
#pragma unroll
        for (int fn = 0; fn < 4; ++fn) {
            const int col = wn * 64 + fn * 16 + frow;
#pragma unroll
            for (int j = 0; j < 4; ++j) {
                const int row = wm * 32 + fm * 16 + fgrp * 4 + j;
                const int ss = (col >> 3) ^ (row & 7);
                Hs[row * 256 + ss * 8 + (col & 7)] = f2bf(fmaxf(acc[fm][fn][j], 0.f));
            }
        }
    __syncthreads();

#pragma unroll
    for (int i = 0; i < 2; ++i)
#pragma unroll
        for (int j = 0; j < 4; ++j) acc[i][j] = f32x4{0.f, 0.f, 0.f, 0.f};

    for (int k0 = 0; k0 < 256; k0 += 32) {
        glds16(gW2 + k0,         &Bs[w * 512]);
        glds16(gW2 + 32768 + k0, &Bs[(w + 8) * 512]);
        __syncthreads();

        short8 af[2], bq[4];
#pragma unroll
        for (int fm = 0; fm < 2; ++fm) {
            const int row = wm * 32 + fm * 16 + frow;
            const int ksg = (k0 >> 3) + fgrp;
            const int ss = ksg ^ (row & 7);
            af[fm] = *reinterpret_cast<const short8*>(&Hs[row * 256 + ss * 8]);
        }
#pragma unroll
        for (int fn = 0; fn < 4; ++fn)
            bq[fn] = *reinterpret_cast<const short8*>(&Bs[(wn * 64 + fn * 16 + frow) * 32 + fslot * 8]);
#pragma unroll
        for (int fm = 0; fm < 2; ++fm)
#pragma unroll
            for (int fn = 0; fn < 4; ++fn)
                acc[fm][fn] = __builtin_amdgcn_mfma_f32_16x16x32_bf16(af[fm], bq[fn], acc[fm][fn], 0, 0, 0);
        __syncthreads();
    }

#pragma unroll
    for (int fm = 0; fm < 2; ++fm)
#pragma unroll
        for (int fn = 0; fn < 4; ++fn) {
            const int col = wn * 64 + fn * 16 + frow;
#pragma unroll
            for (int j = 0; j < 4; ++j) {
                const size_t row = brow + wm * 32 + fm * 16 + fgrp * 4 + j;
                acc[fm][fn][j] += bf2f(X[row * 256 + col]);
            }
        }
#pragma unroll
    for (int fm = 0; fm < 2; ++fm)
#pragma unroll
        for (int j = 0; j < 4; ++j) {
            float s1 = 0.f, s2 = 0.f;
#pragma unroll
            for (int fn = 0; fn < 4; ++fn) { const float x = acc[fm][fn][j]; s1 += x; s2 += x * x; }
#pragma unroll
            for (int o = 1; o < 16; o <<= 1) { s1 += __shfl_xor(s1, o); s2 += __shfl_xor(s2, o); }
            if (frow == 0)
                sdLN[wm * 32 + fm * 16 + fgrp * 4 + j][wn] = make_float2(s1, s2);
        }
    __syncthreads();
#pragma unroll
    for (int fm = 0; fm < 2; ++fm)
#pragma unroll
        for (int j = 0; j < 4; ++j) {
            const int rl = wm * 32 + fm * 16 + fgrp * 4 + j;
            const float2 p0 = sdLN[rl][0], p1 = sdLN[rl][1], p2 = sdLN[rl][2], p3 = sdLN[rl][3];
            const float s1 = p0.x + p1.x + p2.x + p3.x;
            const float s2 = p0.y + p1.y + p2.y + p3.y;
            const float mu = s1 * (1.f / 256.f);
            const float var = s2 * (1.f / 256.f) - mu * mu;
            const float rstd = rsqrtf(var + 1e-5f);
            const size_t row = brow + rl;
#pragma unroll
            for (int fn = 0; fn < 4; ++fn) {
                const int col = wn * 64 + fn * 16 + frow;
                outf[row * 256 + col] = (acc[fm][fn][j] - mu) * rstd * lng[col] + lnb[col];
            }
        }
}

// ---------------------------------------------------------------------------
extern "C" void kernel_launch(void* const* d_in, const int* in_sizes, int n_in,
                              void* d_out, int out_size, void* d_ws, size_t ws_size,
                              hipStream_t stream)
{
    const float* lidar  = (const float*)d_in[0];
    const float* feat   = (const float*)d_in[1];
    const float* ref2d  = (const float*)d_in[2];
    const float* q_pose = (const float*)d_in[5];
    const float* W_off  = (const float*)d_in[6];
    const float* b_off  = (const float*)d_in[7];
    const float* W_attn = (const float*)d_in[8];
    const float* b_attn = (const float*)d_in[9];
    const float* W_val  = (const float*)d_in[10];
    const float* b_val  = (const float*)d_in[11];
    const float* W_out  = (const float*)d_in[12];
    const float* b_out  = (const float*)d_in[13];
    const float* ln1_g  = (const float*)d_in[14];
    const float* ln1_b  = (const float*)d_in[15];
    const float* ffn_w1 = (const float*)d_in[16];
    const float* ffn_w2 = (const float*)d_in[17];
    const float* ln2_g  = (const float*)d_in[18];
    const float* ln2_b  = (const float*)d_in[19];

    float* out = (float*)d_out;
    char*  ws  = (char*)d_ws;

    // byte offsets; high-water ~98.8 MB
    unsigned short* vb     = (unsigned short*)(ws + 0);          // 22,282,240
    unsigned short* oa     = (unsigned short*)(ws + 22282240);   // 25,165,824
    unsigned short* smp    = (unsigned short*)(ws + 47448064);   // 16,777,216
    unsigned short* xln    = (unsigned short*)(ws + 64225280);   // 16,777,216
    unsigned short* lidarb = (unsigned short*)(ws + 81002496);   // 16,777,216
    unsigned short* wt     = (unsigned short*)(ws + 97779712);   //    720,896
    int* perm = (int*)(ws + 98500608);                           //    131,072
    int* bkt  = (int*)(ws + 98631680);                           //    131,072
    int* hist = (int*)(ws + 98762752);                           //      2,048
    int* gcur = (int*)(ws + 98764800);                           //      2,048
    unsigned short* wt_val = wt;
    unsigned short* wt_oa  = wt + 65536;          // [384][256]
    unsigned short* wt_out = wt + 163840;
    unsigned short* wt_f1  = wt + 229376;
    unsigned short* wt_f2  = wt + 294912;

    WtArgs wa;
    wa.src[0] = W_val;  wa.dst[0] = wt_val;          wa.n[0] = 256;
    wa.src[1] = W_off;  wa.dst[1] = wt_oa;           wa.n[1] = 256;
    wa.src[2] = W_attn; wa.dst[2] = wt_oa + 65536;   wa.n[2] = 128;
    wa.src[3] = W_out;  wa.dst[3] = wt_out;          wa.n[3] = 256;
    wa.src[4] = ffn_w1; wa.dst[4] = wt_f1;           wa.n[4] = 256;
    wa.src[5] = ffn_w2; wa.dst[5] = wt_f2;           wa.n[5] = 256;

    // 0. zero bucket histogram
    hipMemsetAsync(hist, 0, 2048, stream);

    // 1. weight transpose + bucket ids + distributed hist
    prep_wt<<<dim3(384, 7), dim3(256), 0, stream>>>(wa, ref2d, bkt, hist);

    // 2. value-proj + off/attn-proj (+lidarb) + scan block (-> gcur)
    valoa_k<<<dim3(VAL_BLK + OA_BLK + 1), dim3(512), 0, stream>>>(
        feat, lidar, q_pose, wt_val, wt_oa, b_val, b_off, b_attn,
        vb, oa, lidarb, hist, gcur);

    // 3. distributed scatter -> perm
    scatter_k<<<dim3(64), dim3(512), 0, stream>>>(bkt, gcur, perm);

    // 4. deformable sampling (+softmax), sorted order -> smp bf16 nq-major
    sampler_k<<<dim3(MQ / 4), dim3(256), 0, stream>>>(oa, ref2d, vb, perm, smp);

    // 5. out-proj + LN1 -> xln bf16
    outproj_k<<<dim3(MQ / 128), dim3(512), 0, stream>>>(
        smp, lidarb, wt_out, b_out, ln1_g, ln1_b, xln);

    // 6. FFN1+FFN2+LN2 -> d_out f32
    ffn_fused<<<dim3(MQ / 64), dim3(512), 0, stream>>>(
        xln, wt_f1, wt_f2, ln2_g, ln2_b, out);
}

// Round 17
// 189.132 us; speedup vs baseline: 1.1206x; 1.0341x over previous
//
#include <hip/hip_runtime.h>
#include <cstdint>

#define EMBED 256
#define HEADS 8
#define LEVELS 4
#define POINTS 4
#define BS 2
#define NQ 16384
#define NV 21760          // 128*128+64*64+32*32+16*16
#define MQ (BS*NQ)        // 32768
#define MV (BS*NV)        // 43520
#define VAL_BLK 340       // MV/128
#define OA_BLK  256       // MQ/128

typedef __attribute__((ext_vector_type(8))) short short8;
typedef __attribute__((ext_vector_type(4))) float f32x4;
typedef __attribute__((ext_vector_type(2))) float f32x2;

__device__ __forceinline__ unsigned short f2bf(float f) {
    unsigned int u = __float_as_uint(f);
    u = (u + 0x7FFFu + ((u >> 16) & 1u)) >> 16;   // RNE
    return (unsigned short)u;
}
__device__ __forceinline__ float bf2f(unsigned short h) {
    return __uint_as_float(((unsigned int)h) << 16);
}
__device__ __forceinline__ void glds16(const unsigned short* g, unsigned short* l) {
    __builtin_amdgcn_global_load_lds((const __attribute__((address_space(1))) void*)g,
                                     (__attribute__((address_space(3))) void*)l, 16, 0, 0);
}

// ---------------------------------------------------------------------------
// prep_wt: y<6 -> Wt[n][k] = bf16(W[k][n]); y==6 -> bucket ids + global hist.
// ---------------------------------------------------------------------------
struct WtArgs {
    const float* src[6];
    unsigned short* dst[6];
    int n[6];
};
__global__ __launch_bounds__(256) void prep_wt(
    WtArgs a, const float* __restrict__ ref2d,
    int* __restrict__ bkt, int* __restrict__ hist)
{
    const int t = threadIdx.x, g = blockIdx.y, bx = blockIdx.x;
    if (g == 6) {
        if (bx < 64) {
#pragma unroll
            for (int i = 0; i < 2; ++i) {
                const int rb = bx * 512 + i * 256 + t;
                const float x = ref2d[(size_t)rb * 8 + 0];
                const float y = ref2d[(size_t)rb * 8 + 1];
                const int qx = min(15, max(0, (int)(x * 16.f)));
                const int qy = min(15, max(0, (int)(y * 16.f)));
                const int bv = (rb >> 14) * 256 + qy * 16 + qx;
                bkt[rb] = bv;
                atomicAdd(&hist[bv], 1);
            }
        }
        return;
    }
    const int N = a.n[g];
    const int e = bx * 256 + t;
    if (e >= 256 * N) return;
    const int k = e / N, n = e - k * N;
    a.dst[g][(size_t)n * 256 + k] = f2bf(a.src[g][e]);
}

// ---------------------------------------------------------------------------
// gemm_core: SOURCE-ORDER reads (sequential), REMAPPED writes (b-major for
// consumers): native row r = n*BS+b  ->  out row = (r&1)*inner + (r>>1).
// ---------------------------------------------------------------------------
template<int NCOLS>
__device__ __forceinline__ void gemm_core(
    unsigned short* As, unsigned short* Bs, int bx, int inner,
    const float* __restrict__ Af, const float* __restrict__ A2f,
    const unsigned short* __restrict__ Bt,
    const float* __restrict__ bias0, const float* __restrict__ bias1,
    unsigned short* __restrict__ lidarb, unsigned short* __restrict__ outh)
{
    constexpr int FN = NCOLS / 64;
    const int t = threadIdx.x, l = t & 63, w = t >> 6;
    const int wm = w >> 2, wn = w & 3;
    const int frow = l & 15, fgrp = l >> 4;
    const size_t brow = (size_t)bx * 128;

    const int fslot = fgrp ^ ((frow & 3) ^ ((frow >> 2) & 3));
    const int srow = l >> 2;
    const int sswz = (l & 3) ^ ((srow & 3) ^ ((srow >> 2) & 3));
    const unsigned short* gB0 = Bt + ((size_t)(w * 16 + srow)) * 256 + sswz * 8;

    const int arow_s = t >> 2, aslot_s = t & 3;
    const size_t srcrow = (brow + arow_s) * 256;     // NATIVE row -> sequential
    const float* srcA = Af + srcrow;
    const float* srcA2 = A2f ? A2f + srcrow : nullptr;
    const int aswz_s = aslot_s ^ ((arow_s & 3) ^ ((arow_s >> 2) & 3));

    f32x4 acc[4][FN];
#pragma unroll
    for (int i = 0; i < 4; ++i)
#pragma unroll
        for (int j = 0; j < FN; ++j) acc[i][j] = f32x4{0.f, 0.f, 0.f, 0.f};

    float4 pA0 = *(const float4*)(srcA + aslot_s * 8);
    float4 pA1 = *(const float4*)(srcA + aslot_s * 8 + 4);
    float4 pC0, pC1;
    if (srcA2) { pC0 = *(const float4*)(srcA2 + aslot_s * 8);
                 pC1 = *(const float4*)(srcA2 + aslot_s * 8 + 4); }

    for (int k0 = 0; k0 < 256; k0 += 32) {
        glds16(gB0 + k0,         &Bs[w * 512]);
        glds16(gB0 + 32768 + k0, &Bs[(w + 8) * 512]);
        if constexpr (NCOLS == 384)
            glds16(gB0 + 65536 + k0, &Bs[(w + 16) * 512]);

        if (lidarb) {   // bf16(lidar) side-copy, native order
            short8 lk;
            lk[0] = (short)f2bf(pA0.x); lk[1] = (short)f2bf(pA0.y);
            lk[2] = (short)f2bf(pA0.z); lk[3] = (short)f2bf(pA0.w);
            lk[4] = (short)f2bf(pA1.x); lk[5] = (short)f2bf(pA1.y);
            lk[6] = (short)f2bf(pA1.z); lk[7] = (short)f2bf(pA1.w);
            *reinterpret_cast<short8*>(lidarb + srcrow + k0 + aslot_s * 8) = lk;
        }

        float c[8] = {pA0.x, pA0.y, pA0.z, pA0.w, pA1.x, pA1.y, pA1.z, pA1.w};
        if (srcA2) {
            c[0] += pC0.x; c[1] += pC0.y; c[2] += pC0.z; c[3] += pC0.w;
            c[4] += pC1.x; c[5] += pC1.y; c[6] += pC1.z; c[7] += pC1.w;
        }
        short8 pk;
#pragma unroll
        for (int i = 0; i < 8; ++i) pk[i] = (short)f2bf(c[i]);
        *reinterpret_cast<short8*>(&As[arow_s * 32 + aswz_s * 8]) = pk;
        if (k0 + 32 < 256) {
            pA0 = *(const float4*)(srcA + k0 + 32 + aslot_s * 8);
            pA1 = *(const float4*)(srcA + k0 + 32 + aslot_s * 8 + 4);
            if (srcA2) { pC0 = *(const float4*)(srcA2 + k0 + 32 + aslot_s * 8);
                         pC1 = *(const float4*)(srcA2 + k0 + 32 + aslot_s * 8 + 4); }
        }
        __syncthreads();

        short8 af[4]; short8 bq[FN];
#pragma unroll
        for (int fm = 0; fm < 4; ++fm)
            af[fm] = *reinterpret_cast<const short8*>(&As[(wm * 64 + fm * 16 + frow) * 32 + fslot * 8]);
#pragma unroll
        for (int fn = 0; fn < FN; ++fn)
            bq[fn] = *reinterpret_cast<const short8*>(&Bs[(wn * (NCOLS / 4) + fn * 16 + frow) * 32 + fslot * 8]);
#pragma unroll
        for (int fm = 0; fm < 4; ++fm)
#pragma unroll
            for (int fn = 0; fn < FN; ++fn)
                acc[fm][fn] = __builtin_amdgcn_mfma_f32_16x16x32_bf16(af[fm], bq[fn], acc[fm][fn], 0, 0, 0);
        __syncthreads();
    }

#pragma unroll
    for (int fn = 0; fn < FN; ++fn) {
        const int col = wn * (NCOLS / 4) + fn * 16 + frow;
        float b;
        if (NCOLS == 384) b = (col < 256) ? bias0[col] : bias1[col - 256];
        else              b = bias0[col];
#pragma unroll
        for (int fm = 0; fm < 4; ++fm)
#pragma unroll
            for (int j = 0; j < 4; ++j) {
                const size_t r = brow + wm * 64 + fm * 16 + fgrp * 4 + j;   // native
                const size_t row = (size_t)((r & 1) ? inner : 0) + (r >> 1); // b-major
                outh[row * NCOLS + col] = f2bf(acc[fm][fn][j] + b);
            }
    }
}

// ---------------------------------------------------------------------------
// valoa_k: [0,340) value-proj -> vb b-major; [340,596) off+attn -> oa
// rb-major (+lidarb native); block 596: scan only -> gcur.
// ---------------------------------------------------------------------------
__global__ __launch_bounds__(512) void valoa_k(
    const float* __restrict__ feat, const float* __restrict__ lidar,
    const float* __restrict__ q_pose,
    const unsigned short* __restrict__ wt_val, const unsigned short* __restrict__ wt_oa,
    const float* __restrict__ b_val, const float* __restrict__ b_off,
    const float* __restrict__ b_attn,
    unsigned short* __restrict__ vb, unsigned short* __restrict__ oa,
    unsigned short* __restrict__ lidarb,
    const int* __restrict__ hist, int* __restrict__ gcur)
{
    __shared__ unsigned short As[128 * 32];
    __shared__ unsigned short Bs[384 * 32];
    const int bx = blockIdx.x;
    if (bx < VAL_BLK) {
        gemm_core<256>(As, Bs, bx, NV, feat, nullptr, wt_val, b_val, nullptr, nullptr, vb);
    } else if (bx < VAL_BLK + OA_BLK) {
        gemm_core<384>(As, Bs, bx - VAL_BLK, NQ, lidar, q_pose, wt_oa, b_off, b_attn, lidarb, oa);
    } else {
        int* s = (int*)As;
        const int t = threadIdx.x;
        const int v = hist[t];
        s[t] = v;
        __syncthreads();
        int acc = v;
#pragma unroll
        for (int o = 1; o < 512; o <<= 1) {
            const int add = (t >= o) ? s[t - o] : 0;
            __syncthreads();
            acc += add;
            s[t] = acc;
            __syncthreads();
        }
        gcur[t] = acc - v;   // exclusive prefix -> global cursor
    }
}

// ---------------------------------------------------------------------------
// scatter_k: distributed scatter via GLOBAL atomics (64 blocks x 512 thr).
// ---------------------------------------------------------------------------
__global__ __launch_bounds__(512) void scatter_k(
    const int* __restrict__ bkt, int* __restrict__ gcur, int* __restrict__ perm)
{
    const int rb = blockIdx.x * 512 + threadIdx.x;
    const int pos = atomicAdd(&gcur[bkt[rb]], 1);
    perm[pos] = rb;
}

// ---------------------------------------------------------------------------
// sampler (R12 verbatim addressing: oa rb-major, v b-major): paired
// ds_read_b128 descriptors + f32x2 pk-fma. 4 q/block, 256 thr.
// ---------------------------------------------------------------------------
__global__ __launch_bounds__(256) void sampler_k(
    const unsigned short* __restrict__ oa,    // [b*NQ+q][384]: off | aw
    const float* __restrict__ ref2d,          // [MQ][8] (b*NQ+q major)
    const unsigned short* __restrict__ v,     // [b*NV+n][256]
    const int* __restrict__ perm,             // [MQ] bucket-sorted rb ids
    unsigned short* __restrict__ outh)        // [MQ][256] nq-major
{
    const int bid = blockIdx.x;
    const int sbid = (bid & 7) * (MQ / 4 / 8) + (bid >> 3);   // XCD swizzle
    const int q0 = sbid * 4;
    const int t = threadIdx.x;

    __shared__ __align__(16) uint2 s_d[4][8][74];  // [tq][h][c*18+lp], padded

#pragma unroll
    for (int it = 0; it < 2; ++it) {     // 512 descriptors, 2 per thread
        const int item = t + it * 256;
        const int tq = item >> 7, hlp = item & 127;
        const int h = hlp >> 4, lp = hlp & 15, li = lp >> 2;
        const int rb = perm[q0 + tq];
        const int b = rb >> 14;

        const float2 refv = *(const float2*)(ref2d + (size_t)rb * 8 + li * 2);
        const ushort2 offu = *(const ushort2*)(oa + (size_t)rb * 384 + hlp * 2);
        const float ax = bf2f(oa[(size_t)rb * 384 + 256 + hlp]);

        // softmax over the 16-lane (q,h) group
        float m = ax;
#pragma unroll
        for (int o = 1; o < 16; o <<= 1) m = fmaxf(m, __shfl_xor(m, o));
        const float e = __expf(ax - m);
        float sden = e;
#pragma unroll
        for (int o = 1; o < 16; o <<= 1) sden += __shfl_xor(sden, o);
        const float a = e / sden;

        const int Wl[4]  = {128, 64, 32, 16};
        const int S0l[4] = {0, 16384, 20480, 21504};
        const int Wi = Wl[li]; const float Wf = (float)Wi;
        const float x = (refv.x + bf2f(offu.x) / Wf) * Wf - 0.5f;
        const float y = (refv.y + bf2f(offu.y) / Wf) * Wf - 0.5f;
        const float x0f = floorf(x), y0f = floorf(y);
        const float lx = x - x0f, ly = y - y0f;
        const int x0 = (int)x0f, y0 = (int)y0f;
        const float cw[4] = {(1.f - lx) * (1.f - ly) * a, lx * (1.f - ly) * a,
                             (1.f - lx) * ly * a,          lx * ly * a};
        const int base = b * NV + S0l[li];
#pragma unroll
        for (int c = 0; c < 4; ++c) {
            const int xi = x0 + (c & 1), yi = y0 + (c >> 1);
            const bool val = (xi >= 0) & (xi < Wi) & (yi >= 0) & (yi < Wi);
            const int xc = min(max(xi, 0), Wi - 1), yc = min(max(yi, 0), Wi - 1);
            const unsigned int ofs = (unsigned int)(base + yc * Wi + xc) * 256u + h * 32;
            s_d[tq][h][c * 18 + lp] = make_uint2(__float_as_uint(val ? cw[c] : 0.f), ofs);
        }
    }
    __syncthreads();

    const int tq = t >> 6, l = t & 63, h = l >> 3, dq = l & 7;
    const int rb = perm[q0 + tq], b = rb >> 14, qi = rb & (NQ - 1);
    const unsigned short* vd = v + dq * 4;
    const uint2* dp = &s_d[tq][h][0];
    f32x2 acc01 = {0.f, 0.f}, acc23 = {0.f, 0.f};
#pragma unroll
    for (int c = 0; c < 4; ++c) {
#pragma unroll
        for (int i = 0; i < 8; ++i) {
            const uint4 dd = *(const uint4*)(dp + c * 18 + i * 2);  // 2 descriptors
            {
                const uint2 raw = *(const uint2*)(vd + dd.y);
                const float w0 = __uint_as_float(dd.x);
                f32x2 v01; v01.x = __uint_as_float(raw.x << 16);
                           v01.y = __uint_as_float(raw.x & 0xFFFF0000u);
                f32x2 v23; v23.x = __uint_as_float(raw.y << 16);
                           v23.y = __uint_as_float(raw.y & 0xFFFF0000u);
                acc01 += w0 * v01;
                acc23 += w0 * v23;
            }
            {
                const uint2 raw = *(const uint2*)(vd + dd.w);
                const float w1 = __uint_as_float(dd.z);
                f32x2 v01; v01.x = __uint_as_float(raw.x << 16);
                           v01.y = __uint_as_float(raw.x & 0xFFFF0000u);
                f32x2 v23; v23.x = __uint_as_float(raw.y << 16);
                           v23.y = __uint_as_float(raw.y & 0xFFFF0000u);
                acc01 += w1 * v01;
                acc23 += w1 * v23;
            }
        }
    }
    ushort4 o;
    o.x = f2bf(acc01.x); o.y = f2bf(acc01.y);
    o.z = f2bf(acc23.x); o.w = f2bf(acc23.y);
    *(ushort4*)(outh + (size_t)(qi * BS + b) * 256 + h * 32 + dq * 4) = o;
}

// ---------------------------------------------------------------------------
// outproj_k: 128-row tile; x = LN1(smp@Wo + b_out + lidarb) -> xln bf16.
// ---------------------------------------------------------------------------
__global__ __launch_bounds__(512) void outproj_k(
    const unsigned short* __restrict__ smp, const unsigned short* __restrict__ lidarb,
    const unsigned short* __restrict__ Wo, const float* __restrict__ b_out,
    const float* __restrict__ ln1g, const float* __restrict__ ln1b,
    unsigned short* __restrict__ xln)
{
    __shared__ unsigned short As[128 * 32];
    __shared__ unsigned short Bs[256 * 32];
    __shared__ float2 sdLN[128][4];

    const int t = threadIdx.x, l = t & 63, w = t >> 6;
    const int wm = w >> 2, wn = w & 3;
    const int frow = l & 15, fgrp = l >> 4;
    const size_t brow = (size_t)blockIdx.x * 128;

    const int fslot = fgrp ^ ((frow & 3) ^ ((frow >> 2) & 3));
    const int srow = l >> 2;
    const int sswz = (l & 3) ^ ((srow & 3) ^ ((srow >> 2) & 3));

    const unsigned short* gA = smp + (brow + (size_t)(w * 16 + srow)) * 256 + sswz * 8;
    const unsigned short* gB = Wo + ((size_t)(w * 16 + srow)) * 256 + sswz * 8;

    f32x4 acc[4][4];
#pragma unroll
    for (int i = 0; i < 4; ++i)
#pragma unroll
        for (int j = 0; j < 4; ++j) acc[i][j] = f32x4{0.f, 0.f, 0.f, 0.f};

    for (int k0 = 0; k0 < 256; k0 += 32) {
        glds16(gB + k0,         &Bs[w * 512]);
        glds16(gB + 32768 + k0, &Bs[(w + 8) * 512]);
        glds16(gA + k0, &As[w * 512]);
        __syncthreads();

        short8 af[4], bq[4];
#pragma unroll
        for (int fm = 0; fm < 4; ++fm)
            af[fm] = *reinterpret_cast<const short8*>(&As[(wm * 64 + fm * 16 + frow) * 32 + fslot * 8]);
#pragma unroll
        for (int fn = 0; fn < 4; ++fn)
            bq[fn] = *reinterpret_cast<const short8*>(&Bs[(wn * 64 + fn * 16 + frow) * 32 + fslot * 8]);
#pragma unroll
        for (int fm = 0; fm < 4; ++fm)
#pragma unroll
            for (int fn = 0; fn < 4; ++fn)
                acc[fm][fn] = __builtin_amdgcn_mfma_f32_16x16x32_bf16(af[fm], bq[fn], acc[fm][fn], 0, 0, 0);
        __syncthreads();
    }

    int cols[4];
#pragma unroll
    for (int fn = 0; fn < 4; ++fn) cols[fn] = wn * 64 + fn * 16 + frow;

#pragma unroll
    for (int fm = 0; fm < 4; ++fm)
#pragma unroll
        for (int j = 0; j < 4; ++j) {
            const size_t row = brow + wm * 64 + fm * 16 + fgrp * 4 + j;
#pragma unroll
            for (int fn = 0; fn < 4; ++fn)
                acc[fm][fn][j] += b_out[cols[fn]] + bf2f(lidarb[row * 256 + cols[fn]]);
        }

#pragma unroll
    for (int fm = 0; fm < 4; ++fm)
#pragma unroll
        for (int j = 0; j < 4; ++j) {
            float s1 = 0.f, s2 = 0.f;
#pragma unroll
            for (int fn = 0; fn < 4; ++fn) { const float x = acc[fm][fn][j]; s1 += x; s2 += x * x; }
#pragma unroll
            for (int o = 1; o < 16; o <<= 1) { s1 += __shfl_xor(s1, o); s2 += __shfl_xor(s2, o); }
            if (frow == 0)
                sdLN[wm * 64 + fm * 16 + fgrp * 4 + j][wn] = make_float2(s1, s2);
        }
    __syncthreads();
    float gv[4], bv[4];
#pragma unroll
    for (int fn = 0; fn < 4; ++fn) { gv[fn] = ln1g[cols[fn]]; bv[fn] = ln1b[cols[fn]]; }
#pragma unroll
    for (int fm = 0; fm < 4; ++fm)
#pragma unroll
        for (int j = 0; j < 4; ++j) {
            const int rl = wm * 64 + fm * 16 + fgrp * 4 + j;
            const float2 p0 = sdLN[rl][0], p1 = sdLN[rl][1], p2 = sdLN[rl][2], p3 = sdLN[rl][3];
            const float s1 = p0.x + p1.x + p2.x + p3.x;
            const float s2 = p0.y + p1.y + p2.y + p3.y;
            const float mu = s1 * (1.f / 256.f);
            const float var = s2 * (1.f / 256.f) - mu * mu;
            const float rstd = rsqrtf(var + 1e-5f);
            const size_t row = brow + rl;
#pragma unroll
            for (int fn = 0; fn < 4; ++fn)
                xln[row * 256 + cols[fn]] = f2bf((acc[fm][fn][j] - mu) * rstd * gv[fn] + bv[fn]);
        }
}

// ---------------------------------------------------------------------------
// ffn_fused: h = relu(X@W1); out = LN2(h@W2 + X), f32 out.
// ---------------------------------------------------------------------------
__global__ __launch_bounds__(512) void ffn_fused(
    const unsigned short* __restrict__ X,
    const unsigned short* __restrict__ W1t, const unsigned short* __restrict__ W2t,
    const float* __restrict__ lng, const float* __restrict__ lnb,
    float* __restrict__ outf)
{
    __shared__ unsigned short As[64 * 32];
    __shared__ unsigned short Bs[256 * 32];
    __shared__ unsigned short Hs[64 * 256];
    __shared__ float2 sdLN[64][4];

    const int t = threadIdx.x, l = t & 63, w = t >> 6;
    const int wm = w >> 2, wn = w & 3;
    const int frow = l & 15, fgrp = l >> 4;
    const size_t brow = (size_t)blockIdx.x * 64;

    const int fslot = fgrp ^ ((frow & 3) ^ ((frow >> 2) & 3));
    const int srow = l >> 2;
    const int sswz = (l & 3) ^ ((srow & 3) ^ ((srow >> 2) & 3));

    const unsigned short* gX  = X + (brow + (size_t)((w & 3) * 16 + srow)) * 256 + sswz * 8;
    const unsigned short* gW1 = W1t + ((size_t)(w * 16 + srow)) * 256 + sswz * 8;
    const unsigned short* gW2 = W2t + ((size_t)(w * 16 + srow)) * 256 + sswz * 8;

    f32x4 acc[2][4];

#pragma unroll
    for (int i = 0; i < 2; ++i)
#pragma unroll
        for (int j = 0; j < 4; ++j) acc[i][j] = f32x4{0.f, 0.f, 0.f, 0.f};

    for (int k0 = 0; k0 < 256; k0 += 32) {
        glds16(gW1 + k0,         &Bs[w * 512]);
        glds16(gW1 + 32768 + k0, &Bs[(w + 8) * 512]);
        if (w < 4) glds16(gX + k0, &As[w * 512]);
        __syncthreads();

        short8 af[2], bq[4];
#pragma unroll
        for (int fm = 0; fm < 2; ++fm)
            af[fm] = *reinterpret_cast<const short8*>(&As[(wm * 32 + fm * 16 + frow) * 32 + fslot * 8]);
#pragma unroll
        for (int fn = 0; fn < 4; ++fn)
            bq[fn] = *reinterpret_cast<const short8*>(&Bs[(wn * 64 + fn * 16 + frow) * 32 + fslot * 8]);
#pragma unroll
        for (int fm = 0; fm < 2; ++fm)
#pragma unroll
            for (int fn = 0; fn < 4; ++fn)
                acc[fm][fn] = __builtin_amdgcn_mfma_f32_16x16x32_bf16(af[fm], bq[fn], acc[fm][fn], 0, 0, 0);
        __syncthreads();
    }

#pragma unroll
    for (int fm = 0; fm < 2; ++fm)
#pragma unroll
        for (int fn = 0; fn < 4; ++fn) {
            const int col = wn * 64 + fn * 16 + frow;
#pragma unroll
            for (int j = 0; j < 4; ++j) {
                const int row = wm * 32 + fm * 16 + fgrp * 4 + j;
                const int ss = (col >> 3) ^ (row & 7);
                Hs[row * 256 + ss * 8 + (col & 7)] = f2bf(fmaxf(acc[fm][fn][j], 0.f));
            }
        }
    __syncthreads();

#pragma unroll
    for (int i = 0; i < 2; ++i)
#pragma unroll
        for (int j = 0; j < 4; ++j) acc[i][j] = f32x4{0.f, 0.f, 0.f, 0.f};

    for (int k0 = 0; k0 < 256; k0 += 32) {
        glds16(gW2 + k0,         &Bs[w * 512]);
        glds16(gW2 + 32768 + k0, &Bs[(w + 8) * 512]);
        __syncthreads();

        short8 af[2], bq[4];
#pragma unroll
        for (int fm = 0; fm < 2; ++fm) {
            const int row = wm * 32 + fm * 16 + frow;
            const int ksg = (k0 >> 3) + fgrp;
            const int ss = ksg ^ (row & 7);
            af[fm] = *reinterpret_cast<const short8*>(&Hs[row * 256 + ss * 8]);
        }
#pragma unroll
        for (int fn = 0; fn < 4; ++fn)
            bq[fn] = *reinterpret_cast<const short8*>(&Bs[(wn * 64 + fn * 16 + frow) * 32 + fslot * 8]);
#pragma unroll
        for (int fm = 0; fm < 2; ++fm)
#pragma unroll
            for (int fn = 0; fn < 4; ++fn)
                acc[fm][fn] = __builtin_amdgcn_mfma_f32_16x16x32_bf16(af[fm], bq[fn], acc[fm][fn], 0, 0, 0);
        __syncthreads();
    }

#pragma unroll
    for (int fm = 0; fm < 2; ++fm)
#pragma unroll
        for (int fn = 0; fn < 4; ++fn) {
            const int col = wn * 64 + fn * 16 + frow;
#pragma unroll
            for (int j = 0; j < 4; ++j) {
                const size_t row = brow + wm * 32 + fm * 16 + fgrp * 4 + j;
                acc[fm][fn][j] += bf2f(X[row * 256 + col]);
            }
        }
#pragma unroll
    for (int fm = 0; fm < 2; ++fm)
#pragma unroll
        for (int j = 0; j < 4; ++j) {
            float s1 = 0.f, s2 = 0.f;
#pragma unroll
            for (int fn = 0; fn < 4; ++fn) { const float x = acc[fm][fn][j]; s1 += x; s2 += x * x; }
#pragma unroll
            for (int o = 1; o < 16; o <<= 1) { s1 += __shfl_xor(s1, o); s2 += __shfl_xor(s2, o); }
            if (frow == 0)
                sdLN[wm * 32 + fm * 16 + fgrp * 4 + j][wn] = make_float2(s1, s2);
        }
    __syncthreads();
#pragma unroll
    for (int fm = 0; fm < 2; ++fm)
#pragma unroll
        for (int j = 0; j < 4; ++j) {
            const int rl = wm * 32 + fm * 16 + fgrp * 4 + j;
            const float2 p0 = sdLN[rl][0], p1 = sdLN[rl][1], p2 = sdLN[rl][2], p3 = sdLN[rl][3];
            const float s1 = p0.x + p1.x + p2.x + p3.x;
            const float s2 = p0.y + p1.y + p2.y + p3.y;
            const float mu = s1 * (1.f / 256.f);
            const float var = s2 * (1.f / 256.f) - mu * mu;
            const float rstd = rsqrtf(var + 1e-5f);
            const size_t row = brow + rl;
#pragma unroll
            for (int fn = 0; fn < 4; ++fn) {
                const int col = wn * 64 + fn * 16 + frow;
                outf[row * 256 + col] = (acc[fm][fn][j] - mu) * rstd * lng[col] + lnb[col];
            }
        }
}

// ---------------------------------------------------------------------------
extern "C" void kernel_launch(void* const* d_in, const int* in_sizes, int n_in,
                              void* d_out, int out_size, void* d_ws, size_t ws_size,
                              hipStream_t stream)
{
    const float* lidar  = (const float*)d_in[0];
    const float* feat   = (const float*)d_in[1];
    const float* ref2d  = (const float*)d_in[2];
    const float* q_pose = (const float*)d_in[5];
    const float* W_off  = (const float*)d_in[6];
    const float* b_off  = (const float*)d_in[7];
    const float* W_attn = (const float*)d_in[8];
    const float* b_attn = (const float*)d_in[9];
    const float* W_val  = (const float*)d_in[10];
    const float* b_val  = (const float*)d_in[11];
    const float* W_out  = (const float*)d_in[12];
    const float* b_out  = (const float*)d_in[13];
    const float* ln1_g  = (const float*)d_in[14];
    const float* ln1_b  = (const float*)d_in[15];
    const float* ffn_w1 = (const float*)d_in[16];
    const float* ffn_w2 = (const float*)d_in[17];
    const float* ln2_g  = (const float*)d_in[18];
    const float* ln2_b  = (const float*)d_in[19];

    float* out = (float*)d_out;
    char*  ws  = (char*)d_ws;

    // byte offsets; high-water ~98.8 MB
    unsigned short* vb     = (unsigned short*)(ws + 0);          // 22,282,240
    unsigned short* oa     = (unsigned short*)(ws + 22282240);   // 25,165,824
    unsigned short* smp    = (unsigned short*)(ws + 47448064);   // 16,777,216
    unsigned short* xln    = (unsigned short*)(ws + 64225280);   // 16,777,216
    unsigned short* lidarb = (unsigned short*)(ws + 81002496);   // 16,777,216
    unsigned short* wt     = (unsigned short*)(ws + 97779712);   //    720,896
    int* perm = (int*)(ws + 98500608);                           //    131,072
    int* bkt  = (int*)(ws + 98631680);                           //    131,072
    int* hist = (int*)(ws + 98762752);                           //      2,048
    int* gcur = (int*)(ws + 98764800);                           //      2,048
    unsigned short* wt_val = wt;
    unsigned short* wt_oa  = wt + 65536;          // [384][256]
    unsigned short* wt_out = wt + 163840;
    unsigned short* wt_f1  = wt + 229376;
    unsigned short* wt_f2  = wt + 294912;

    WtArgs wa;
    wa.src[0] = W_val;  wa.dst[0] = wt_val;          wa.n[0] = 256;
    wa.src[1] = W_off;  wa.dst[1] = wt_oa;           wa.n[1] = 256;
    wa.src[2] = W_attn; wa.dst[2] = wt_oa + 65536;   wa.n[2] = 128;
    wa.src[3] = W_out;  wa.dst[3] = wt_out;          wa.n[3] = 256;
    wa.src[4] = ffn_w1; wa.dst[4] = wt_f1;           wa.n[4] = 256;
    wa.src[5] = ffn_w2; wa.dst[5] = wt_f2;           wa.n[5] = 256;

    // 0. zero bucket histogram
    hipMemsetAsync(hist, 0, 2048, stream);

    // 1. weight transpose + bucket ids + distributed hist
    prep_wt<<<dim3(384, 7), dim3(256), 0, stream>>>(wa, ref2d, bkt, hist);

    // 2. value-proj (-> vb b-major) + off/attn (-> oa rb-major, +lidarb)
    //    + scan block (-> gcur)
    valoa_k<<<dim3(VAL_BLK + OA_BLK + 1), dim3(512), 0, stream>>>(
        feat, lidar, q_pose, wt_val, wt_oa, b_val, b_off, b_attn,
        vb, oa, lidarb, hist, gcur);

    // 3. distributed scatter -> perm
    scatter_k<<<dim3(64), dim3(512), 0, stream>>>(bkt, gcur, perm);

    // 4. deformable sampling (+softmax), sorted order -> smp bf16 nq-major
    sampler_k<<<dim3(MQ / 4), dim3(256), 0, stream>>>(oa, ref2d, vb, perm, smp);

    // 5. out-proj + LN1 -> xln bf16
    outproj_k<<<dim3(MQ / 128), dim3(512), 0, stream>>>(
        smp, lidarb, wt_out, b_out, ln1_g, ln1_b, xln);

    // 6. FFN1+FFN2+LN2 -> d_out f32
    ffn_fused<<<dim3(MQ / 64), dim3(512), 0, stream>>>(
        xln, wt_f1, wt_f2, ln2_g, ln2_b, out);
}